// Round 1
// baseline (1795.513 us; speedup 1.0000x reference)
//
#include <hip/hip_runtime.h>
#include <math.h>

#define S_LEN 2048
#define HID 2048
#define NH 16
#define DK 128
#define DV 128
#define CS 64
#define NC 32
#define KEY_DIM 2048
#define VAL_DIM 2048
#define CONV_DIM 6144
#define QSCALE 0.08838834764831845f  /* 1/sqrt(128) */

__device__ __forceinline__ float sigmoidf_(float x){ return 1.f/(1.f+expf(-x)); }

// ---------------- workspace layout (floats) ----------------
constexpr size_t N_MIXED = (size_t)S_LEN*CONV_DIM;
constexpr size_t OFF_MIXED = 0;
constexpr size_t OFF_CONVO = OFF_MIXED + N_MIXED;
constexpr size_t OFF_Z     = OFF_CONVO + N_MIXED;
constexpr size_t OFF_BRAW  = OFF_Z + (size_t)S_LEN*VAL_DIM;
constexpr size_t OFF_ARAW  = OFF_BRAW + (size_t)S_LEN*NH;
constexpr size_t OFF_BETA  = OFF_ARAW + (size_t)S_LEN*NH;
constexpr size_t OFF_G     = OFF_BETA + (size_t)S_LEN*NH;
constexpr size_t OFF_KCD   = OFF_G + (size_t)S_LEN*NH;
constexpr size_t OFF_AI    = OFF_KCD + (size_t)NH*NC*CS*DK;
constexpr size_t OFF_AT    = OFF_AI + (size_t)NH*NC*CS*CS;
constexpr size_t OFF_BM    = OFF_AT + (size_t)NH*NC*DK*DK;
constexpr size_t OFF_SALL  = OFF_BM + (size_t)NH*NC*DK*DV;
constexpr size_t OFF_CORE  = OFF_SALL + (size_t)NH*NC*DK*DV;

// ---------------- GEMM: C[m][n] = sum_k A[m][k] * B[n][k] (both K-contiguous) ----------------
__global__ __launch_bounds__(256) void gemm_bt(const float* __restrict__ A,
    const float* __restrict__ B, float* __restrict__ C, int M, int N, int Kd)
{
  __shared__ float As[8][128];
  __shared__ float Bs[8][128];
  const int tid = threadIdx.x;
  const int tx = tid & 15, ty = tid >> 4;
  const int row0 = blockIdx.y*128, col0 = blockIdx.x*128;
  float acc[8][8];
#pragma unroll
  for (int i=0;i<8;i++)
#pragma unroll
    for (int j=0;j<8;j++) acc[i][j]=0.f;
  const int lr = tid >> 1;
  const int lk = (tid & 1)*4;
  const float* Ap = A + (size_t)(row0+lr)*Kd + lk;
  const float* Bp = B + (size_t)(col0+lr)*Kd + lk;
#pragma unroll 1
  for (int k0=0; k0<Kd; k0+=8){
    float4 av = *(const float4*)(Ap + k0);
    float4 bv = *(const float4*)(Bp + k0);
    __syncthreads();
    As[lk+0][lr]=av.x; As[lk+1][lr]=av.y; As[lk+2][lr]=av.z; As[lk+3][lr]=av.w;
    Bs[lk+0][lr]=bv.x; Bs[lk+1][lr]=bv.y; Bs[lk+2][lr]=bv.z; Bs[lk+3][lr]=bv.w;
    __syncthreads();
#pragma unroll
    for (int kk=0;kk<8;kk++){
      float4 a0 = *(const float4*)&As[kk][ty*4];
      float4 a1 = *(const float4*)&As[kk][64+ty*4];
      float4 b0 = *(const float4*)&Bs[kk][tx*4];
      float4 b1 = *(const float4*)&Bs[kk][64+tx*4];
      float ar[8]={a0.x,a0.y,a0.z,a0.w,a1.x,a1.y,a1.z,a1.w};
      float br[8]={b0.x,b0.y,b0.z,b0.w,b1.x,b1.y,b1.z,b1.w};
#pragma unroll
      for (int i=0;i<8;i++)
#pragma unroll
        for (int j=0;j<8;j++) acc[i][j] += ar[i]*br[j];
    }
  }
#pragma unroll
  for (int i=0;i<8;i++){
    int r = row0 + ((i<4)?(ty*4+i):(64+ty*4+i-4));
    float* cp = C + (size_t)r*N + col0;
    *(float4*)(cp + tx*4)    = make_float4(acc[i][0],acc[i][1],acc[i][2],acc[i][3]);
    *(float4*)(cp + 64+tx*4) = make_float4(acc[i][4],acc[i][5],acc[i][6],acc[i][7]);
  }
}

// ---------------- b/a projections (N=16 each) ----------------
__global__ __launch_bounds__(128) void k_ba(const float* __restrict__ hid,
   const float* __restrict__ bw, const float* __restrict__ aw,
   float* __restrict__ braw, float* __restrict__ araw)
{
  __shared__ float red[128];
  const int s = blockIdx.x;
  const int t = threadIdx.x;
  const int o = t & 31, pg = t >> 5;
  const float* hrow = hid + (size_t)s*HID;
  const float* wrow = (o<16) ? (bw + (size_t)o*HID) : (aw + (size_t)(o-16)*HID);
  float acc = 0.f;
  for (int h = pg; h < HID; h += 4) acc += hrow[h]*wrow[h];
  red[t] = acc;
  __syncthreads();
  if (t < 32){
    float tot = red[t]+red[t+32]+red[t+64]+red[t+96];
    if (t < 16) braw[s*NH+t] = tot; else araw[s*NH+(t-16)] = tot;
  }
}

// ---------------- beta = sigmoid(b); G = within-chunk cumsum of g ----------------
__global__ __launch_bounds__(64) void k_beta_g(const float* __restrict__ braw,
  const float* __restrict__ araw, const float* __restrict__ dtb,
  const float* __restrict__ alog, float* __restrict__ beta, float* __restrict__ G)
{
  const int b = blockIdx.x;
  const int n = b & (NH-1), c = b >> 4;
  const int t = threadIdx.x;
  const int s = c*CS + t;
  float x = araw[s*NH+n] + dtb[n];
  float sp = (x > 20.f) ? x : log1pf(expf(x));
  float g = -expf(alog[n]) * sp;
#pragma unroll
  for (int off=1; off<64; off<<=1){
    float u = __shfl_up(g, off, 64);
    if (t >= off) g += u;
  }
  G[s*NH+n] = g;
  float bb = braw[s*NH+n];
  beta[s*NH+n] = 1.f/(1.f+expf(-bb));
}

// ---------------- depthwise causal conv K=4 + SiLU ----------------
__global__ __launch_bounds__(256) void k_conv(const float* __restrict__ mixed,
  const float* __restrict__ cw, float* __restrict__ convo)
{
  const int ch = blockIdx.x*256 + threadIdx.x;
  const int s = blockIdx.y;
  const float w0=cw[ch*4], w1=cw[ch*4+1], w2=cw[ch*4+2], w3=cw[ch*4+3];
  float acc = mixed[(size_t)s*CONV_DIM + ch]*w3;
  if (s>=1) acc += mixed[(size_t)(s-1)*CONV_DIM + ch]*w2;
  if (s>=2) acc += mixed[(size_t)(s-2)*CONV_DIM + ch]*w1;
  if (s>=3) acc += mixed[(size_t)(s-3)*CONV_DIM + ch]*w0;
  convo[(size_t)s*CONV_DIM + ch] = acc * sigmoidf_(acc);
}

// ---------------- in-place l2norm of q (scaled) and k, per (s,head) ----------------
__global__ __launch_bounds__(256) void k_l2norm(float* __restrict__ convo)
{
  const int t = threadIdx.x;
  const int lane = t & 63, w = t >> 6;
  const int s = blockIdx.x;
  const int n = blockIdx.y*4 + w;
  {
    float* q = convo + (size_t)s*CONV_DIM + n*DK;
    float q0 = q[lane], q1 = q[lane+64];
    float ss = q0*q0 + q1*q1;
#pragma unroll
    for (int m=1;m<64;m<<=1) ss += __shfl_xor(ss, m, 64);
    float r = rsqrtf(ss + 1e-6f) * QSCALE;
    q[lane] = q0*r; q[lane+64] = q1*r;
  }
  {
    float* k = convo + (size_t)s*CONV_DIM + KEY_DIM + n*DK;
    float k0 = k[lane], k1 = k[lane+64];
    float ss = k0*k0 + k1*k1;
#pragma unroll
    for (int m=1;m<64;m<<=1) ss += __shfl_xor(ss, m, 64);
    float r = rsqrtf(ss + 1e-6f);
    k[lane] = k0*r; k[lane+64] = k1*r;
  }
}

// ---------------- per (head,chunk): L, attn=(I-L)^-1, ai, value (in-place over v), kcd ----------------
__global__ __launch_bounds__(256) void k_chunk1(float* __restrict__ convo,
  const float* __restrict__ G, const float* __restrict__ beta,
  float* __restrict__ ai_g, float* __restrict__ kcd_g)
{
  __shared__ float KT[128][76];   // KT[d][i] = k[i][d]
  __shared__ float LT[64][65];    // L, then attn in-place
  __shared__ float reds[4][64];
  __shared__ float Gs[64], bets[64], kes[64];
  const int c = blockIdx.x, n = blockIdx.y;
  const int t = threadIdx.x;
  const int tx = t & 15, ty = t >> 4;
  const int s0 = c*CS;
  if (t < 64){
    float gv = G[(s0+t)*NH+n], bv = beta[(s0+t)*NH+n];
    Gs[t]=gv; bets[t]=bv; kes[t]=bv*expf(gv);
  }
  __syncthreads();
  for (int idx=t; idx<CS*DK; idx+=256){
    int i = idx>>7, d = idx&127;
    KT[d][i] = convo[(size_t)(s0+i)*CONV_DIM + KEY_DIM + n*DK + d];
  }
  __syncthreads();
  // ---- L[i][j] = -beta_i (k_i.k_j) exp(min(G_i-G_j,10)) for j<i ----
  {
    const int i0=ty*4, j0=tx*4;
    float l[4][4]={};
    for (int d=0; d<DK; d++){
      float4 ki = *(const float4*)&KT[d][i0];
      float4 kj = *(const float4*)&KT[d][j0];
      float kiv[4]={ki.x,ki.y,ki.z,ki.w};
      float kjv[4]={kj.x,kj.y,kj.z,kj.w};
#pragma unroll
      for (int a=0;a<4;a++)
#pragma unroll
        for (int b=0;b<4;b++) l[a][b] += kiv[a]*kjv[b];
    }
#pragma unroll
    for (int a=0;a<4;a++)
#pragma unroll
      for (int b=0;b<4;b++){
        int i=i0+a, j=j0+b;
        LT[i][j] = (j<i) ? (-bets[i]*l[a][b]*expf(fminf(Gs[i]-Gs[j],10.f))) : 0.f;
      }
  }
  __syncthreads();
  // ---- ai[i][j] = (q_i.k_j)*dm for j<=i ----
  {
    const int i0=ty*4, j0=tx*4;
    float acc[4][4]={};
    for (int d=0; d<DK; d++){
      float4 kj = *(const float4*)&KT[d][j0];
      float kjv[4]={kj.x,kj.y,kj.z,kj.w};
      float qv[4];
#pragma unroll
      for (int a=0;a<4;a++) qv[a] = convo[(size_t)(s0+i0+a)*CONV_DIM + n*DK + d];
#pragma unroll
      for (int a=0;a<4;a++)
#pragma unroll
        for (int b=0;b<4;b++) acc[a][b] += qv[a]*kjv[b];
    }
    size_t ab = ((size_t)(n*NC+c))*CS*CS;
#pragma unroll
    for (int a=0;a<4;a++)
#pragma unroll
      for (int b=0;b<4;b++){
        int i=i0+a, j=j0+b;
        ai_g[ab + i*CS + j] = (j<=i) ? acc[a][b]*expf(fminf(Gs[i]-Gs[j],10.f)) : 0.f;
      }
  }
  __syncthreads();
  // ---- forward substitution: LT := (I-L)^{-1} (unit lower triangular) ----
  if (t==0) LT[0][0]=1.f;
  __syncthreads();
#pragma unroll 1
  for (int i=1;i<64;i++){
    const int j = t&63, pg = t>>6;
    float part=0.f;
    if (j < i){
      for (int p=j+1+pg; p<i; p+=4) part += LT[i][p]*LT[p][j];
    }
    reds[pg][j]=part;
    __syncthreads();
    if (t < 64){
      if (t < i) LT[i][t] += reds[0][t]+reds[1][t]+reds[2][t]+reds[3][t];
      else if (t==i) LT[i][i] = 1.f;
    }
    __syncthreads();
  }
  // ---- value = attn @ (v*beta), overwrite v region ----
  {
    const int i0=ty*4, d0=tx*8;
    float acc[4][8]={};
    for (int p=0;p<CS;p++){
      float lt[4];
#pragma unroll
      for (int a=0;a<4;a++) lt[a]=LT[i0+a][p];
      const float bp = bets[p];
      const float* vr = convo + (size_t)(s0+p)*CONV_DIM + 2*KEY_DIM + n*DV + d0;
      float4 v0=*(const float4*)vr, v1=*(const float4*)(vr+4);
      float vv[8]={v0.x*bp,v0.y*bp,v0.z*bp,v0.w*bp,v1.x*bp,v1.y*bp,v1.z*bp,v1.w*bp};
#pragma unroll
      for (int a=0;a<4;a++)
#pragma unroll
        for (int b=0;b<8;b++) acc[a][b] += lt[a]*vv[b];
    }
    __syncthreads();   // all reads of original v done before overwrite
#pragma unroll
    for (int a=0;a<4;a++){
      float* orow = convo + (size_t)(s0+i0+a)*CONV_DIM + 2*KEY_DIM + n*DV + d0;
      *(float4*)orow     = make_float4(acc[a][0],acc[a][1],acc[a][2],acc[a][3]);
      *(float4*)(orow+4) = make_float4(acc[a][4],acc[a][5],acc[a][6],acc[a][7]);
    }
  }
  // ---- kcd = attn @ (k*beta*exp(G)) ----
  {
    const int i0=(t&7)*8, d0=(t>>3)*4;
    float acc[8][4]={};
    for (int p=0;p<CS;p++){
      const float ke = kes[p];
      float lt[8];
#pragma unroll
      for (int a=0;a<8;a++) lt[a]=LT[i0+a][p];
      float kv[4];
#pragma unroll
      for (int b=0;b<4;b++) kv[b]=KT[d0+b][p]*ke;
#pragma unroll
      for (int a=0;a<8;a++)
#pragma unroll
        for (int b=0;b<4;b++) acc[a][b]+=lt[a]*kv[b];
    }
    size_t kb = ((size_t)(n*NC+c))*CS*DK;
#pragma unroll
    for (int a=0;a<8;a++)
      *(float4*)&kcd_g[kb + (size_t)(i0+a)*DK + d0] =
          make_float4(acc[a][0],acc[a][1],acc[a][2],acc[a][3]);
  }
}

// ---------------- per (head,chunk): A_c = e^gl I - K~^T KCD (stored transposed), B_c = K~^T value ----------------
__global__ __launch_bounds__(256) void k_chunk2(const float* __restrict__ convo,
  const float* __restrict__ kcd_g, const float* __restrict__ G,
  float* __restrict__ AT_g, float* __restrict__ B_g)
{
  __shared__ float Ks[32][132], Cs[32][132], Vs[32][132];
  __shared__ float Gsh[64];
  const int c = blockIdx.x, n = blockIdx.y;
  const int t = threadIdx.x;
  const int tx = t&15, ty = t>>4;
  if (t<64) Gsh[t] = G[(c*CS+t)*NH+n];
  __syncthreads();
  const float gl = Gsh[63];
  float accA[8][8]={}, accB[8][8]={};
#pragma unroll 1
  for (int ib=0; ib<2; ib++){
    __syncthreads();
    for (int fi=t; fi<32*32; fi+=256){
      int i = fi>>5, dq=(fi&31)*4;
      int sg = c*CS + ib*32 + i;
      float ef = expf(gl - Gsh[ib*32+i]);
      float4 kv = *(const float4*)&convo[(size_t)sg*CONV_DIM + KEY_DIM + n*DK + dq];
      *(float4*)&Ks[i][dq] = make_float4(kv.x*ef,kv.y*ef,kv.z*ef,kv.w*ef);
      *(float4*)&Cs[i][dq] = *(const float4*)&kcd_g[((size_t)(n*NC+c)*CS + ib*32+i)*DK + dq];
      *(float4*)&Vs[i][dq] = *(const float4*)&convo[(size_t)sg*CONV_DIM + 2*KEY_DIM + n*DV + dq];
    }
    __syncthreads();
    for (int i=0;i<32;i++){
      float krx[8], cpy[8], kry[8], vdx[8];
      float4 u,v;
      u=*(const float4*)&Ks[i][tx*4]; v=*(const float4*)&Ks[i][64+tx*4];
      krx[0]=u.x;krx[1]=u.y;krx[2]=u.z;krx[3]=u.w;krx[4]=v.x;krx[5]=v.y;krx[6]=v.z;krx[7]=v.w;
      u=*(const float4*)&Cs[i][ty*4]; v=*(const float4*)&Cs[i][64+ty*4];
      cpy[0]=u.x;cpy[1]=u.y;cpy[2]=u.z;cpy[3]=u.w;cpy[4]=v.x;cpy[5]=v.y;cpy[6]=v.z;cpy[7]=v.w;
      u=*(const float4*)&Ks[i][ty*4]; v=*(const float4*)&Ks[i][64+ty*4];
      kry[0]=u.x;kry[1]=u.y;kry[2]=u.z;kry[3]=u.w;kry[4]=v.x;kry[5]=v.y;kry[6]=v.z;kry[7]=v.w;
      u=*(const float4*)&Vs[i][tx*4]; v=*(const float4*)&Vs[i][64+tx*4];
      vdx[0]=u.x;vdx[1]=u.y;vdx[2]=u.z;vdx[3]=u.w;vdx[4]=v.x;vdx[5]=v.y;vdx[6]=v.z;vdx[7]=v.w;
#pragma unroll
      for (int a=0;a<8;a++)
#pragma unroll
        for (int b=0;b<8;b++){
          accA[a][b] += cpy[a]*krx[b];   // (K~^T KCD)[r][p] accumulated as [p(a/ty)][r(b/tx)]
          accB[a][b] += kry[a]*vdx[b];   // B[r(a/ty)][d(b/tx)]
        }
    }
  }
  const float egl = expf(gl);
  const size_t ab = (size_t)(n*NC+c)*DK*DK;
#pragma unroll
  for (int a=0;a<8;a++){
    int p = (a<4)?(ty*4+a):(64+ty*4+a-4);
#pragma unroll
    for (int bq=0;bq<2;bq++){
      int r0 = (bq==0)?(tx*4):(64+tx*4);
      float o[4];
#pragma unroll
      for (int j=0;j<4;j++){
        int r = r0+j;
        float val = -accA[a][bq*4+j];
        if (p==r) val += egl;
        o[j]=val;
      }
      *(float4*)&AT_g[ab + (size_t)p*DK + r0] = make_float4(o[0],o[1],o[2],o[3]);
    }
  }
  const size_t bb = (size_t)(n*NC+c)*DK*DV;
#pragma unroll
  for (int a=0;a<8;a++){
    int r = (a<4)?(ty*4+a):(64+ty*4+a-4);
#pragma unroll
    for (int bq=0;bq<2;bq++){
      int d0 = (bq==0)?(tx*4):(64+tx*4);
      *(float4*)&B_g[bb + (size_t)r*DV + d0] =
        make_float4(accB[a][bq*4+0],accB[a][bq*4+1],accB[a][bq*4+2],accB[a][bq*4+3]);
    }
  }
}

// ---------------- sequential scan: S_{c+1} = A_c S_c + B_c; store pre-states ----------------
__global__ __launch_bounds__(256) void k_scan(const float* __restrict__ AT_g,
  const float* __restrict__ B_g, float* __restrict__ Sall)
{
  __shared__ float Ash[64][132];
  __shared__ float SL[128][20];
  const int n = blockIdx.x, cg = blockIdx.y;
  const int t = threadIdx.x;
  const int r0 = (t&63)*2, d0 = (t>>6)*4;
  for (int idx=t; idx<128*20; idx+=256) (&SL[0][0])[idx]=0.f;
  __syncthreads();
#pragma unroll 1
  for (int c=0;c<NC;c++){
    const size_t mb = (size_t)(n*NC+c)*DK;
#pragma unroll
    for (int rr=0;rr<2;rr++){
      float4 sv = *(float4*)&SL[r0+rr][d0];
      *(float4*)&Sall[(mb + r0+rr)*DV + cg*16 + d0] = sv;
    }
    float acc[2][4]={};
#pragma unroll 1
    for (int pb=0;pb<2;pb++){
      __syncthreads();
      const size_t abase = (mb + pb*64)*DK;
#pragma unroll
      for (int q=0;q<8;q++){
        int fi = t + q*256;
        int p = fi>>5, rq=(fi&31)*4;
        *(float4*)&Ash[p][rq] = *(const float4*)&AT_g[abase + (size_t)p*DK + rq];
      }
      __syncthreads();
      for (int pp=0;pp<64;pp++){
        float a0=Ash[pp][r0], a1=Ash[pp][r0+1];
        float4 sv=*(float4*)&SL[pb*64+pp][d0];
        float s4[4]={sv.x,sv.y,sv.z,sv.w};
#pragma unroll
        for (int dd=0;dd<4;dd++){ acc[0][dd]+=a0*s4[dd]; acc[1][dd]+=a1*s4[dd]; }
      }
    }
    __syncthreads();
    float4 b0=*(const float4*)&B_g[(mb + r0)*DV + cg*16 + d0];
    float4 b1=*(const float4*)&B_g[(mb + r0+1)*DV + cg*16 + d0];
    float4 n0=make_float4(acc[0][0]+b0.x, acc[0][1]+b0.y, acc[0][2]+b0.z, acc[0][3]+b0.w);
    float4 n1=make_float4(acc[1][0]+b1.x, acc[1][1]+b1.y, acc[1][2]+b1.z, acc[1][3]+b1.w);
    *(float4*)&SL[r0][d0]=n0; *(float4*)&SL[r0+1][d0]=n1;
    __syncthreads();
  }
}

// ---------------- outputs: out = q~ @ S_c + ai @ (value - kcd @ S_c) ----------------
__global__ __launch_bounds__(256) void k_out(const float* __restrict__ convo,
  const float* __restrict__ kcd_g, const float* __restrict__ ai_g,
  const float* __restrict__ Sall, const float* __restrict__ G,
  float* __restrict__ core)
{
  __shared__ float Ssh[32][132];
  __shared__ float Wsh[64][132];
  __shared__ float egs[64];
  const int c = blockIdx.x, n = blockIdx.y;
  const int t = threadIdx.x;
  const int tx = t&15, ty = t>>4;
  const int i0 = ty*4, d0 = tx*8;
  const int s0 = c*CS;
  if (t<64) egs[t] = expf(G[(s0+t)*NH+n]);
  float wacc[4][8]={}, oacc[4][8]={};
  const size_t mb = (size_t)(n*NC+c)*DK;
  const size_t kb = (size_t)(n*NC+c)*CS*DK;
#pragma unroll 1
  for (int rb=0;rb<4;rb++){
    __syncthreads();
    for (int fi=t; fi<32*32; fi+=256){
      int rr=fi>>5, dq=(fi&31)*4;
      *(float4*)&Ssh[rr][dq] = *(const float4*)&Sall[(mb + rb*32+rr)*DV + dq];
    }
    __syncthreads();
    for (int r2=0;r2<32;r2++){
      int r = rb*32+r2;
      float4 sa=*(const float4*)&Ssh[r2][d0], sb=*(const float4*)&Ssh[r2][d0+4];
      float sv[8]={sa.x,sa.y,sa.z,sa.w,sb.x,sb.y,sb.z,sb.w};
      float qv[4], kv[4];
#pragma unroll
      for (int a=0;a<4;a++){
        qv[a] = convo[(size_t)(s0+i0+a)*CONV_DIM + n*DK + r] * egs[i0+a];
        kv[a] = kcd_g[kb + (size_t)(i0+a)*DK + r];
      }
#pragma unroll
      for (int a=0;a<4;a++)
#pragma unroll
        for (int b=0;b<8;b++){
          oacc[a][b] += qv[a]*sv[b];
          wacc[a][b] += kv[a]*sv[b];
        }
    }
  }
  __syncthreads();
#pragma unroll
  for (int a=0;a<4;a++){
    const float* vr = convo + (size_t)(s0+i0+a)*CONV_DIM + 2*KEY_DIM + n*DV + d0;
    float4 v0=*(const float4*)vr, v1=*(const float4*)(vr+4);
    *(float4*)&Wsh[i0+a][d0]   = make_float4(v0.x-wacc[a][0],v0.y-wacc[a][1],v0.z-wacc[a][2],v0.w-wacc[a][3]);
    *(float4*)&Wsh[i0+a][d0+4] = make_float4(v1.x-wacc[a][4],v1.y-wacc[a][5],v1.z-wacc[a][6],v1.w-wacc[a][7]);
  }
  __syncthreads();
  const size_t aib = (size_t)(n*NC+c)*CS*CS;
  for (int j=0;j<CS;j++){
    float4 w0=*(const float4*)&Wsh[j][d0], w1=*(const float4*)&Wsh[j][d0+4];
    float wv[8]={w0.x,w0.y,w0.z,w0.w,w1.x,w1.y,w1.z,w1.w};
    float av[4];
#pragma unroll
    for (int a=0;a<4;a++) av[a]=ai_g[aib + (size_t)(i0+a)*CS + j];
#pragma unroll
    for (int a=0;a<4;a++)
#pragma unroll
      for (int b=0;b<8;b++) oacc[a][b]+=av[a]*wv[b];
  }
#pragma unroll
  for (int a=0;a<4;a++){
    float* cr = core + (size_t)(s0+i0+a)*VAL_DIM + n*DV + d0;
    *(float4*)cr     = make_float4(oacc[a][0],oacc[a][1],oacc[a][2],oacc[a][3]);
    *(float4*)(cr+4) = make_float4(oacc[a][4],oacc[a][5],oacc[a][6],oacc[a][7]);
  }
}

// ---------------- RMSNorm * norm_w * silu(z), in-place over z ----------------
__global__ __launch_bounds__(256) void k_norm_gate(const float* __restrict__ core,
  float* __restrict__ z, const float* __restrict__ nw)
{
  const int t=threadIdx.x, lane=t&63, w=t>>6;
  const int row = blockIdx.x*4 + w;
  const float* cr = core + (size_t)row*DV;
  float c0=cr[lane], c1=cr[lane+64];
  float ss=c0*c0+c1*c1;
#pragma unroll
  for (int m=1;m<64;m<<=1) ss += __shfl_xor(ss,m,64);
  float sc = rsqrtf(ss*(1.f/128.f) + 1e-6f);
  float* zr = z + (size_t)row*DV;
  float z0=zr[lane], z1=zr[lane+64];
  zr[lane]    = c0*sc*nw[lane]    * (z0*sigmoidf_(z0));
  zr[lane+64] = c1*sc*nw[lane+64] * (z1*sigmoidf_(z1));
}

extern "C" void kernel_launch(void* const* d_in, const int* in_sizes, int n_in,
                              void* d_out, int out_size, void* d_ws, size_t ws_size,
                              hipStream_t stream)
{
  (void)in_sizes; (void)n_in; (void)out_size; (void)ws_size;
  const float* hid  = (const float*)d_in[0];
  const float* qkvw = (const float*)d_in[1];
  const float* zw   = (const float*)d_in[2];
  const float* bw   = (const float*)d_in[3];
  const float* aw   = (const float*)d_in[4];
  const float* ow   = (const float*)d_in[5];
  const float* cw   = (const float*)d_in[6];
  const float* dtb  = (const float*)d_in[7];
  const float* alog = (const float*)d_in[8];
  const float* nw   = (const float*)d_in[9];

  float* ws    = (float*)d_ws;
  float* mixed = ws + OFF_MIXED;
  float* convo = ws + OFF_CONVO;
  float* zbuf  = ws + OFF_Z;
  float* braw  = ws + OFF_BRAW;
  float* araw  = ws + OFF_ARAW;
  float* beta  = ws + OFF_BETA;
  float* G     = ws + OFF_G;
  float* kcd   = ws + OFF_KCD;
  float* ai    = ws + OFF_AI;
  float* AT    = ws + OFF_AT;
  float* Bm    = ws + OFF_BM;
  float* Sall  = ws + OFF_SALL;
  float* core  = ws + OFF_CORE;

  gemm_bt<<<dim3(CONV_DIM/128, S_LEN/128), 256, 0, stream>>>(hid, qkvw, mixed, S_LEN, CONV_DIM, HID);
  gemm_bt<<<dim3(VAL_DIM/128,  S_LEN/128), 256, 0, stream>>>(hid, zw,   zbuf,  S_LEN, VAL_DIM, HID);
  k_ba<<<S_LEN, 128, 0, stream>>>(hid, bw, aw, braw, araw);
  k_beta_g<<<NH*NC, 64, 0, stream>>>(braw, araw, dtb, alog, beta, G);
  k_conv<<<dim3(CONV_DIM/256, S_LEN), 256, 0, stream>>>(mixed, cw, convo);
  k_l2norm<<<dim3(S_LEN, NH/4), 256, 0, stream>>>(convo);
  k_chunk1<<<dim3(NC, NH), 256, 0, stream>>>(convo, G, beta, ai, kcd);
  k_chunk2<<<dim3(NC, NH), 256, 0, stream>>>(convo, kcd, G, AT, Bm);
  k_scan<<<dim3(NH, 8), 256, 0, stream>>>(AT, Bm, Sall);
  k_out<<<dim3(NC, NH), 256, 0, stream>>>(convo, kcd, ai, Sall, G, core);
  k_norm_gate<<<S_LEN*NH/4, 256, 0, stream>>>(core, zbuf, nw);
  gemm_bt<<<dim3(HID/128, S_LEN/128), 256, 0, stream>>>(zbuf, ow, (float*)d_out, S_LEN, HID, VAL_DIM);
}

// Round 2
// 820.590 us; speedup vs baseline: 2.1881x; 2.1881x over previous
//
#include <hip/hip_runtime.h>
#include <math.h>

#define S_LEN 2048
#define HID 2048
#define NH 16
#define DK 128
#define DV 128
#define CS 64
#define NC 32
#define KEY_DIM 2048
#define VAL_DIM 2048
#define CONV_DIM 6144
#define QSCALE 0.08838834764831845f  /* 1/sqrt(128) */

typedef unsigned short u16;
typedef unsigned int u32;
typedef __bf16 bf16x8 __attribute__((ext_vector_type(8)));
typedef float f32x4 __attribute__((ext_vector_type(4)));

__device__ __forceinline__ float sigmoidf_(float x){ return 1.f/(1.f+expf(-x)); }
__device__ __forceinline__ u16 f2bf(float x){
  u32 u = __float_as_uint(x);
  return (u16)((u + 0x7fffu + ((u>>16)&1u)) >> 16);
}

// ---------------- workspace layout (float units) ----------------
constexpr size_t OFF_HIDBF  = 0;          // 2,097,152 fl  (bf16 S*HID)   dead after gemms
constexpr size_t OFF_QKVWBF = 2097152;    // 6,291,456 fl                 dead after gemm qkv
constexpr size_t OFF_ZWBF   = 8388608;    // 2,097,152 fl                 dead after gemm z
constexpr size_t OFF_OWBF   = 10485760;   // 2,097,152 fl                 live till end
constexpr size_t OFF_GATED  = 12582912;   // 2,097,152 fl (bf16 S*VAL)    live till end
constexpr size_t OFF_MIXED  = 14680064;   // 12,582,912 fl                dead after conv
constexpr size_t OFF_CONVO  = 27262976;   // 12,582,912 fl
constexpr size_t OFF_Z      = 39845888;   // 4,194,304 fl
constexpr size_t OFF_BRAW   = 44040192;   // 32,768
constexpr size_t OFF_ARAW   = 44072960;   // 32,768
constexpr size_t OFF_BETA   = 44105728;   // 32,768
constexpr size_t OFF_G      = 44138496;   // 32,768
constexpr size_t OFF_KCD    = 44171264;   // 4,194,304
constexpr size_t OFF_AI     = 48365568;   // 2,097,152
constexpr size_t OFF_SALL   = 50462720;   // 8,388,608
constexpr size_t OFF_CORE   = 58851328;   // 4,194,304   (end: 63,045,632 fl = 252.2 MB)
constexpr size_t OFF_AT     = OFF_MIXED;  // 8,388,608  alias: written after mixed is dead
constexpr size_t OFF_BM     = 0;          // 8,388,608  alias: hidbf+qkvwbf region, dead by then

// ---------------- f32 -> bf16 cast (8 elems/thread) ----------------
__global__ __launch_bounds__(256) void k_cast8(const float* __restrict__ in,
                                               u16* __restrict__ out, int n8)
{
  int i = blockIdx.x*256 + threadIdx.x;
  if (i >= n8) return;
  const float4 a = *(const float4*)(in + (size_t)i*8);
  const float4 b = *(const float4*)(in + (size_t)i*8 + 4);
  uint4 o;
  o.x = (u32)f2bf(a.x) | ((u32)f2bf(a.y)<<16);
  o.y = (u32)f2bf(a.z) | ((u32)f2bf(a.w)<<16);
  o.z = (u32)f2bf(b.x) | ((u32)f2bf(b.y)<<16);
  o.w = (u32)f2bf(b.z) | ((u32)f2bf(b.w)<<16);
  *(uint4*)(out + (size_t)i*8) = o;
}

// ---------------- async global->LDS, 16B per lane ----------------
__device__ __forceinline__ void gload16(const u16* g, u16* l){
  __builtin_amdgcn_global_load_lds(
      (__attribute__((address_space(1))) void*)(void*)g,
      (__attribute__((address_space(3))) void*)l, 16, 0, 0);
}

// ---------------- bf16 MFMA GEMM: C[m][n] = sum_k A[m][k]*B[n][k] ----------------
// A: M x Kd bf16 row-major, B: N x Kd bf16 row-major, C: M x N f32.
// 128x128 tile, BK=32, 4 waves in 2x2, each wave 64x64 via 4x4 16x16x32 MFMAs.
__global__ __launch_bounds__(256) void gemm_bf(const u16* __restrict__ A,
    const u16* __restrict__ B, float* __restrict__ C, int M, int N, int Kd)
{
  __shared__ u16 As[128*32];
  __shared__ u16 Bs[128*32];
  const int tid = threadIdx.x;
  const int w = tid>>6, lane = tid&63;
  const int wr = w>>1, wc = w&1;
  const int row0 = blockIdx.y*128, col0 = blockIdx.x*128;

  f32x4 acc[4][4] = {};

  // staging: 8 chunks of 1KB per matrix; wave w owns chunks {2w, 2w+1}
  const int sr = lane>>2;         // row within 16-row chunk
  const int sk = (lane&3)*8;      // k offset (bf16 elems)
  const u16* Ag0 = A + (size_t)(row0 + (2*w  )*16 + sr)*Kd + sk;
  const u16* Ag1 = A + (size_t)(row0 + (2*w+1)*16 + sr)*Kd + sk;
  const u16* Bg0 = B + (size_t)(col0 + (2*w  )*16 + sr)*Kd + sk;
  const u16* Bg1 = B + (size_t)(col0 + (2*w+1)*16 + sr)*Kd + sk;
  u16* Al0 = &As[(2*w  )*16*32];
  u16* Al1 = &As[(2*w+1)*16*32];
  u16* Bl0 = &Bs[(2*w  )*16*32];
  u16* Bl1 = &Bs[(2*w+1)*16*32];

  const int fr = lane&15, fc = (lane>>4)*8;
  const int arow0 = (wr*64 + fr)*32 + fc;   // +m*16*32 per fragment
  const int brow0 = (wc*64 + fr)*32 + fc;

  for (int k0=0; k0<Kd; k0+=32){
    __syncthreads();
    gload16(Ag0 + k0, Al0);
    gload16(Ag1 + k0, Al1);
    gload16(Bg0 + k0, Bl0);
    gload16(Bg1 + k0, Bl1);
    __syncthreads();
    bf16x8 af[4], bfr[4];
#pragma unroll
    for (int m=0;m<4;m++) af[m]  = *(const bf16x8*)&As[arow0 + m*16*32];
#pragma unroll
    for (int n=0;n<4;n++) bfr[n] = *(const bf16x8*)&Bs[brow0 + n*16*32];
#pragma unroll
    for (int m=0;m<4;m++)
#pragma unroll
      for (int n=0;n<4;n++)
        acc[m][n] = __builtin_amdgcn_mfma_f32_16x16x32_bf16(af[m], bfr[n], acc[m][n], 0,0,0);
  }

  // C/D layout: col = lane&15, row = (lane>>4)*4 + j   [m89-verified]
  const int cr = (lane>>4)*4, cc = lane&15;
#pragma unroll
  for (int m=0;m<4;m++)
#pragma unroll
    for (int n=0;n<4;n++){
      float* cp = C + (size_t)(row0 + wr*64 + m*16 + cr)*N + (col0 + wc*64 + n*16 + cc);
#pragma unroll
      for (int j=0;j<4;j++) cp[(size_t)j*N] = acc[m][n][j];
    }
}

// ---------------- b/a projections (N=16 each) ----------------
__global__ __launch_bounds__(128) void k_ba(const float* __restrict__ hid,
   const float* __restrict__ bw, const float* __restrict__ aw,
   float* __restrict__ braw, float* __restrict__ araw)
{
  __shared__ float red[128];
  const int s = blockIdx.x;
  const int t = threadIdx.x;
  const int o = t & 31, pg = t >> 5;
  const float* hrow = hid + (size_t)s*HID;
  const float* wrow = (o<16) ? (bw + (size_t)o*HID) : (aw + (size_t)(o-16)*HID);
  float acc = 0.f;
  for (int h = pg; h < HID; h += 4) acc += hrow[h]*wrow[h];
  red[t] = acc;
  __syncthreads();
  if (t < 32){
    float tot = red[t]+red[t+32]+red[t+64]+red[t+96];
    if (t < 16) braw[s*NH+t] = tot; else araw[s*NH+(t-16)] = tot;
  }
}

// ---------------- beta = sigmoid(b); G = within-chunk cumsum of g ----------------
__global__ __launch_bounds__(64) void k_beta_g(const float* __restrict__ braw,
  const float* __restrict__ araw, const float* __restrict__ dtb,
  const float* __restrict__ alog, float* __restrict__ beta, float* __restrict__ G)
{
  const int b = blockIdx.x;
  const int n = b & (NH-1), c = b >> 4;
  const int t = threadIdx.x;
  const int s = c*CS + t;
  float x = araw[s*NH+n] + dtb[n];
  float sp = (x > 20.f) ? x : log1pf(expf(x));
  float g = -expf(alog[n]) * sp;
#pragma unroll
  for (int off=1; off<64; off<<=1){
    float u = __shfl_up(g, off, 64);
    if (t >= off) g += u;
  }
  G[s*NH+n] = g;
  float bb = braw[s*NH+n];
  beta[s*NH+n] = 1.f/(1.f+expf(-bb));
}

// ---------------- depthwise causal conv K=4 + SiLU ----------------
__global__ __launch_bounds__(256) void k_conv(const float* __restrict__ mixed,
  const float* __restrict__ cw, float* __restrict__ convo)
{
  const int ch = blockIdx.x*256 + threadIdx.x;
  const int s = blockIdx.y;
  const float w0=cw[ch*4], w1=cw[ch*4+1], w2=cw[ch*4+2], w3=cw[ch*4+3];
  float acc = mixed[(size_t)s*CONV_DIM + ch]*w3;
  if (s>=1) acc += mixed[(size_t)(s-1)*CONV_DIM + ch]*w2;
  if (s>=2) acc += mixed[(size_t)(s-2)*CONV_DIM + ch]*w1;
  if (s>=3) acc += mixed[(size_t)(s-3)*CONV_DIM + ch]*w0;
  convo[(size_t)s*CONV_DIM + ch] = acc * sigmoidf_(acc);
}

// ---------------- in-place l2norm of q (scaled) and k, per (s,head) ----------------
__global__ __launch_bounds__(256) void k_l2norm(float* __restrict__ convo)
{
  const int t = threadIdx.x;
  const int lane = t & 63, w = t >> 6;
  const int s = blockIdx.x;
  const int n = blockIdx.y*4 + w;
  {
    float* q = convo + (size_t)s*CONV_DIM + n*DK;
    float q0 = q[lane], q1 = q[lane+64];
    float ss = q0*q0 + q1*q1;
#pragma unroll
    for (int m=1;m<64;m<<=1) ss += __shfl_xor(ss, m, 64);
    float r = rsqrtf(ss + 1e-6f) * QSCALE;
    q[lane] = q0*r; q[lane+64] = q1*r;
  }
  {
    float* k = convo + (size_t)s*CONV_DIM + KEY_DIM + n*DK;
    float k0 = k[lane], k1 = k[lane+64];
    float ss = k0*k0 + k1*k1;
#pragma unroll
    for (int m=1;m<64;m<<=1) ss += __shfl_xor(ss, m, 64);
    float r = rsqrtf(ss + 1e-6f);
    k[lane] = k0*r; k[lane+64] = k1*r;
  }
}

// ---------------- per (head,chunk): L, attn=(I-L)^-1, ai, value (in-place over v), kcd ----------------
__global__ __launch_bounds__(256) void k_chunk1(float* __restrict__ convo,
  const float* __restrict__ G, const float* __restrict__ beta,
  float* __restrict__ ai_g, float* __restrict__ kcd_g)
{
  __shared__ float KT[128][76];   // KT[d][i] = k[i][d]
  __shared__ float LT[64][65];    // L, then attn in-place
  __shared__ float reds[4][64];
  __shared__ float Gs[64], bets[64], kes[64];
  const int c = blockIdx.x, n = blockIdx.y;
  const int t = threadIdx.x;
  const int tx = t & 15, ty = t >> 4;
  const int s0 = c*CS;
  if (t < 64){
    float gv = G[(s0+t)*NH+n], bv = beta[(s0+t)*NH+n];
    Gs[t]=gv; bets[t]=bv; kes[t]=bv*expf(gv);
  }
  __syncthreads();
  for (int idx=t; idx<CS*DK; idx+=256){
    int i = idx>>7, d = idx&127;
    KT[d][i] = convo[(size_t)(s0+i)*CONV_DIM + KEY_DIM + n*DK + d];
  }
  __syncthreads();
  {
    const int i0=ty*4, j0=tx*4;
    float l[4][4]={};
    for (int d=0; d<DK; d++){
      float4 ki = *(const float4*)&KT[d][i0];
      float4 kj = *(const float4*)&KT[d][j0];
      float kiv[4]={ki.x,ki.y,ki.z,ki.w};
      float kjv[4]={kj.x,kj.y,kj.z,kj.w};
#pragma unroll
      for (int a=0;a<4;a++)
#pragma unroll
        for (int b=0;b<4;b++) l[a][b] += kiv[a]*kjv[b];
    }
#pragma unroll
    for (int a=0;a<4;a++)
#pragma unroll
      for (int b=0;b<4;b++){
        int i=i0+a, j=j0+b;
        LT[i][j] = (j<i) ? (-bets[i]*l[a][b]*expf(fminf(Gs[i]-Gs[j],10.f))) : 0.f;
      }
  }
  __syncthreads();
  {
    const int i0=ty*4, j0=tx*4;
    float acc[4][4]={};
    for (int d=0; d<DK; d++){
      float4 kj = *(const float4*)&KT[d][j0];
      float kjv[4]={kj.x,kj.y,kj.z,kj.w};
      float qv[4];
#pragma unroll
      for (int a=0;a<4;a++) qv[a] = convo[(size_t)(s0+i0+a)*CONV_DIM + n*DK + d];
#pragma unroll
      for (int a=0;a<4;a++)
#pragma unroll
        for (int b=0;b<4;b++) acc[a][b] += qv[a]*kjv[b];
    }
    size_t ab = ((size_t)(n*NC+c))*CS*CS;
#pragma unroll
    for (int a=0;a<4;a++)
#pragma unroll
      for (int b=0;b<4;b++){
        int i=i0+a, j=j0+b;
        ai_g[ab + i*CS + j] = (j<=i) ? acc[a][b]*expf(fminf(Gs[i]-Gs[j],10.f)) : 0.f;
      }
  }
  __syncthreads();
  if (t==0) LT[0][0]=1.f;
  __syncthreads();
#pragma unroll 1
  for (int i=1;i<64;i++){
    const int j = t&63, pg = t>>6;
    float part=0.f;
    if (j < i){
      for (int p=j+1+pg; p<i; p+=4) part += LT[i][p]*LT[p][j];
    }
    reds[pg][j]=part;
    __syncthreads();
    if (t < 64){
      if (t < i) LT[i][t] += reds[0][t]+reds[1][t]+reds[2][t]+reds[3][t];
      else if (t==i) LT[i][i] = 1.f;
    }
    __syncthreads();
  }
  {
    const int i0=ty*4, d0=tx*8;
    float acc[4][8]={};
    for (int p=0;p<CS;p++){
      float lt[4];
#pragma unroll
      for (int a=0;a<4;a++) lt[a]=LT[i0+a][p];
      const float bp = bets[p];
      const float* vr = convo + (size_t)(s0+p)*CONV_DIM + 2*KEY_DIM + n*DV + d0;
      float4 v0=*(const float4*)vr, v1=*(const float4*)(vr+4);
      float vv[8]={v0.x*bp,v0.y*bp,v0.z*bp,v0.w*bp,v1.x*bp,v1.y*bp,v1.z*bp,v1.w*bp};
#pragma unroll
      for (int a=0;a<4;a++)
#pragma unroll
        for (int b=0;b<8;b++) acc[a][b] += lt[a]*vv[b];
    }
    __syncthreads();
#pragma unroll
    for (int a=0;a<4;a++){
      float* orow = convo + (size_t)(s0+i0+a)*CONV_DIM + 2*KEY_DIM + n*DV + d0;
      *(float4*)orow     = make_float4(acc[a][0],acc[a][1],acc[a][2],acc[a][3]);
      *(float4*)(orow+4) = make_float4(acc[a][4],acc[a][5],acc[a][6],acc[a][7]);
    }
  }
  {
    const int i0=(t&7)*8, d0=(t>>3)*4;
    float acc[8][4]={};
    for (int p=0;p<CS;p++){
      const float ke = kes[p];
      float lt[8];
#pragma unroll
      for (int a=0;a<8;a++) lt[a]=LT[i0+a][p];
      float kv[4];
#pragma unroll
      for (int b=0;b<4;b++) kv[b]=KT[d0+b][p]*ke;
#pragma unroll
      for (int a=0;a<8;a++)
#pragma unroll
        for (int b=0;b<4;b++) acc[a][b]+=lt[a]*kv[b];
    }
    size_t kb = ((size_t)(n*NC+c))*CS*DK;
#pragma unroll
    for (int a=0;a<8;a++)
      *(float4*)&kcd_g[kb + (size_t)(i0+a)*DK + d0] =
          make_float4(acc[a][0],acc[a][1],acc[a][2],acc[a][3]);
  }
}

// ---------------- per (head,chunk): A_c, B_c ----------------
__global__ __launch_bounds__(256) void k_chunk2(const float* __restrict__ convo,
  const float* __restrict__ kcd_g, const float* __restrict__ G,
  float* __restrict__ AT_g, float* __restrict__ B_g)
{
  __shared__ float Ks[32][132], Cs[32][132], Vs[32][132];
  __shared__ float Gsh[64];
  const int c = blockIdx.x, n = blockIdx.y;
  const int t = threadIdx.x;
  const int tx = t&15, ty = t>>4;
  if (t<64) Gsh[t] = G[(c*CS+t)*NH+n];
  __syncthreads();
  const float gl = Gsh[63];
  float accA[8][8]={}, accB[8][8]={};
#pragma unroll 1
  for (int ib=0; ib<2; ib++){
    __syncthreads();
    for (int fi=t; fi<32*32; fi+=256){
      int i = fi>>5, dq=(fi&31)*4;
      int sg = c*CS + ib*32 + i;
      float ef = expf(gl - Gsh[ib*32+i]);
      float4 kv = *(const float4*)&convo[(size_t)sg*CONV_DIM + KEY_DIM + n*DK + dq];
      *(float4*)&Ks[i][dq] = make_float4(kv.x*ef,kv.y*ef,kv.z*ef,kv.w*ef);
      *(float4*)&Cs[i][dq] = *(const float4*)&kcd_g[((size_t)(n*NC+c)*CS + ib*32+i)*DK + dq];
      *(float4*)&Vs[i][dq] = *(const float4*)&convo[(size_t)sg*CONV_DIM + 2*KEY_DIM + n*DV + dq];
    }
    __syncthreads();
    for (int i=0;i<32;i++){
      float krx[8], cpy[8], kry[8], vdx[8];
      float4 u,v;
      u=*(const float4*)&Ks[i][tx*4]; v=*(const float4*)&Ks[i][64+tx*4];
      krx[0]=u.x;krx[1]=u.y;krx[2]=u.z;krx[3]=u.w;krx[4]=v.x;krx[5]=v.y;krx[6]=v.z;krx[7]=v.w;
      u=*(const float4*)&Cs[i][ty*4]; v=*(const float4*)&Cs[i][64+ty*4];
      cpy[0]=u.x;cpy[1]=u.y;cpy[2]=u.z;cpy[3]=u.w;cpy[4]=v.x;cpy[5]=v.y;cpy[6]=v.z;cpy[7]=v.w;
      u=*(const float4*)&Ks[i][ty*4]; v=*(const float4*)&Ks[i][64+ty*4];
      kry[0]=u.x;kry[1]=u.y;kry[2]=u.z;kry[3]=u.w;kry[4]=v.x;kry[5]=v.y;kry[6]=v.z;kry[7]=v.w;
      u=*(const float4*)&Vs[i][tx*4]; v=*(const float4*)&Vs[i][64+tx*4];
      vdx[0]=u.x;vdx[1]=u.y;vdx[2]=u.z;vdx[3]=u.w;vdx[4]=v.x;vdx[5]=v.y;vdx[6]=v.z;vdx[7]=v.w;
#pragma unroll
      for (int a=0;a<8;a++)
#pragma unroll
        for (int b=0;b<8;b++){
          accA[a][b] += cpy[a]*krx[b];
          accB[a][b] += kry[a]*vdx[b];
        }
    }
  }
  const float egl = expf(gl);
  const size_t ab = (size_t)(n*NC+c)*DK*DK;
#pragma unroll
  for (int a=0;a<8;a++){
    int p = (a<4)?(ty*4+a):(64+ty*4+a-4);
#pragma unroll
    for (int bq=0;bq<2;bq++){
      int r0 = (bq==0)?(tx*4):(64+tx*4);
      float o[4];
#pragma unroll
      for (int j=0;j<4;j++){
        int r = r0+j;
        float val = -accA[a][bq*4+j];
        if (p==r) val += egl;
        o[j]=val;
      }
      *(float4*)&AT_g[ab + (size_t)p*DK + r0] = make_float4(o[0],o[1],o[2],o[3]);
    }
  }
  const size_t bb = (size_t)(n*NC+c)*DK*DV;
#pragma unroll
  for (int a=0;a<8;a++){
    int r = (a<4)?(ty*4+a):(64+ty*4+a-4);
#pragma unroll
    for (int bq=0;bq<2;bq++){
      int d0 = (bq==0)?(tx*4):(64+tx*4);
      *(float4*)&B_g[bb + (size_t)r*DV + d0] =
        make_float4(accB[a][bq*4+0],accB[a][bq*4+1],accB[a][bq*4+2],accB[a][bq*4+3]);
    }
  }
}

// ---------------- sequential scan ----------------
__global__ __launch_bounds__(256) void k_scan(const float* __restrict__ AT_g,
  const float* __restrict__ B_g, float* __restrict__ Sall)
{
  __shared__ float Ash[64][132];
  __shared__ float SL[128][20];
  const int n = blockIdx.x, cg = blockIdx.y;
  const int t = threadIdx.x;
  const int r0 = (t&63)*2, d0 = (t>>6)*4;
  for (int idx=t; idx<128*20; idx+=256) (&SL[0][0])[idx]=0.f;
  __syncthreads();
#pragma unroll 1
  for (int c=0;c<NC;c++){
    const size_t mb = (size_t)(n*NC+c)*DK;
#pragma unroll
    for (int rr=0;rr<2;rr++){
      float4 sv = *(float4*)&SL[r0+rr][d0];
      *(float4*)&Sall[(mb + r0+rr)*DV + cg*16 + d0] = sv;
    }
    float acc[2][4]={};
#pragma unroll 1
    for (int pb=0;pb<2;pb++){
      __syncthreads();
      const size_t abase = (mb + pb*64)*DK;
#pragma unroll
      for (int q=0;q<8;q++){
        int fi = t + q*256;
        int p = fi>>5, rq=(fi&31)*4;
        *(float4*)&Ash[p][rq] = *(const float4*)&AT_g[abase + (size_t)p*DK + rq];
      }
      __syncthreads();
      for (int pp=0;pp<64;pp++){
        float a0=Ash[pp][r0], a1=Ash[pp][r0+1];
        float4 sv=*(float4*)&SL[pb*64+pp][d0];
        float s4[4]={sv.x,sv.y,sv.z,sv.w};
#pragma unroll
        for (int dd=0;dd<4;dd++){ acc[0][dd]+=a0*s4[dd]; acc[1][dd]+=a1*s4[dd]; }
      }
    }
    __syncthreads();
    float4 b0=*(const float4*)&B_g[(mb + r0)*DV + cg*16 + d0];
    float4 b1=*(const float4*)&B_g[(mb + r0+1)*DV + cg*16 + d0];
    float4 n0=make_float4(acc[0][0]+b0.x, acc[0][1]+b0.y, acc[0][2]+b0.z, acc[0][3]+b0.w);
    float4 n1=make_float4(acc[1][0]+b1.x, acc[1][1]+b1.y, acc[1][2]+b1.z, acc[1][3]+b1.w);
    *(float4*)&SL[r0][d0]=n0; *(float4*)&SL[r0+1][d0]=n1;
    __syncthreads();
  }
}

// ---------------- outputs ----------------
__global__ __launch_bounds__(256) void k_out(const float* __restrict__ convo,
  const float* __restrict__ kcd_g, const float* __restrict__ ai_g,
  const float* __restrict__ Sall, const float* __restrict__ G,
  float* __restrict__ core)
{
  __shared__ float Ssh[32][132];
  __shared__ float Wsh[64][132];
  __shared__ float egs[64];
  const int c = blockIdx.x, n = blockIdx.y;
  const int t = threadIdx.x;
  const int tx = t&15, ty = t>>4;
  const int i0 = ty*4, d0 = tx*8;
  const int s0 = c*CS;
  if (t<64) egs[t] = expf(G[(s0+t)*NH+n]);
  float wacc[4][8]={}, oacc[4][8]={};
  const size_t mb = (size_t)(n*NC+c)*DK;
  const size_t kb = (size_t)(n*NC+c)*CS*DK;
#pragma unroll 1
  for (int rb=0;rb<4;rb++){
    __syncthreads();
    for (int fi=t; fi<32*32; fi+=256){
      int rr=fi>>5, dq=(fi&31)*4;
      *(float4*)&Ssh[rr][dq] = *(const float4*)&Sall[(mb + rb*32+rr)*DV + dq];
    }
    __syncthreads();
    for (int r2=0;r2<32;r2++){
      int r = rb*32+r2;
      float4 sa=*(const float4*)&Ssh[r2][d0], sb=*(const float4*)&Ssh[r2][d0+4];
      float sv[8]={sa.x,sa.y,sa.z,sa.w,sb.x,sb.y,sb.z,sb.w};
      float qv[4], kv[4];
#pragma unroll
      for (int a=0;a<4;a++){
        qv[a] = convo[(size_t)(s0+i0+a)*CONV_DIM + n*DK + r] * egs[i0+a];
        kv[a] = kcd_g[kb + (size_t)(i0+a)*DK + r];
      }
#pragma unroll
      for (int a=0;a<4;a++)
#pragma unroll
        for (int b=0;b<8;b++){
          oacc[a][b] += qv[a]*sv[b];
          wacc[a][b] += kv[a]*sv[b];
        }
    }
  }
  __syncthreads();
#pragma unroll
  for (int a=0;a<4;a++){
    const float* vr = convo + (size_t)(s0+i0+a)*CONV_DIM + 2*KEY_DIM + n*DV + d0;
    float4 v0=*(const float4*)vr, v1=*(const float4*)(vr+4);
    *(float4*)&Wsh[i0+a][d0]   = make_float4(v0.x-wacc[a][0],v0.y-wacc[a][1],v0.z-wacc[a][2],v0.w-wacc[a][3]);
    *(float4*)&Wsh[i0+a][d0+4] = make_float4(v1.x-wacc[a][4],v1.y-wacc[a][5],v1.z-wacc[a][6],v1.w-wacc[a][7]);
  }
  __syncthreads();
  const size_t aib = (size_t)(n*NC+c)*CS*CS;
  for (int j=0;j<CS;j++){
    float4 w0=*(const float4*)&Wsh[j][d0], w1=*(const float4*)&Wsh[j][d0+4];
    float wv[8]={w0.x,w0.y,w0.z,w0.w,w1.x,w1.y,w1.z,w1.w};
    float av[4];
#pragma unroll
    for (int a=0;a<4;a++) av[a]=ai_g[aib + (size_t)(i0+a)*CS + j];
#pragma unroll
    for (int a=0;a<4;a++)
#pragma unroll
      for (int b=0;b<8;b++) oacc[a][b]+=av[a]*wv[b];
  }
#pragma unroll
  for (int a=0;a<4;a++){
    float* cr = core + (size_t)(s0+i0+a)*VAL_DIM + n*DV + d0;
    *(float4*)cr     = make_float4(oacc[a][0],oacc[a][1],oacc[a][2],oacc[a][3]);
    *(float4*)(cr+4) = make_float4(oacc[a][4],oacc[a][5],oacc[a][6],oacc[a][7]);
  }
}

// ---------------- RMSNorm * norm_w * silu(z) -> bf16 ----------------
__global__ __launch_bounds__(256) void k_norm_gate(const float* __restrict__ core,
  const float* __restrict__ z, const float* __restrict__ nw, u16* __restrict__ gated)
{
  const int t=threadIdx.x, lane=t&63, w=t>>6;
  const int row = blockIdx.x*4 + w;
  const float* cr = core + (size_t)row*DV;
  float c0=cr[lane], c1=cr[lane+64];
  float ss=c0*c0+c1*c1;
#pragma unroll
  for (int m=1;m<64;m<<=1) ss += __shfl_xor(ss,m,64);
  float sc = rsqrtf(ss*(1.f/128.f) + 1e-6f);
  const float* zr = z + (size_t)row*DV;
  float z0=zr[lane], z1=zr[lane+64];
  u16* gr = gated + (size_t)row*DV;
  gr[lane]    = f2bf(c0*sc*nw[lane]    * (z0*sigmoidf_(z0)));
  gr[lane+64] = f2bf(c1*sc*nw[lane+64] * (z1*sigmoidf_(z1)));
}

extern "C" void kernel_launch(void* const* d_in, const int* in_sizes, int n_in,
                              void* d_out, int out_size, void* d_ws, size_t ws_size,
                              hipStream_t stream)
{
  (void)in_sizes; (void)n_in; (void)out_size; (void)ws_size;
  const float* hid  = (const float*)d_in[0];
  const float* qkvw = (const float*)d_in[1];
  const float* zw   = (const float*)d_in[2];
  const float* bw   = (const float*)d_in[3];
  const float* aw   = (const float*)d_in[4];
  const float* ow   = (const float*)d_in[5];
  const float* cw   = (const float*)d_in[6];
  const float* dtb  = (const float*)d_in[7];
  const float* alog = (const float*)d_in[8];
  const float* nw   = (const float*)d_in[9];

  float* ws     = (float*)d_ws;
  u16* hid_bf   = (u16*)(ws + OFF_HIDBF);
  u16* qkvw_bf  = (u16*)(ws + OFF_QKVWBF);
  u16* zw_bf    = (u16*)(ws + OFF_ZWBF);
  u16* ow_bf    = (u16*)(ws + OFF_OWBF);
  u16* gated_bf = (u16*)(ws + OFF_GATED);
  float* mixed  = ws + OFF_MIXED;
  float* convo  = ws + OFF_CONVO;
  float* zbuf   = ws + OFF_Z;
  float* braw   = ws + OFF_BRAW;
  float* araw   = ws + OFF_ARAW;
  float* beta   = ws + OFF_BETA;
  float* G      = ws + OFF_G;
  float* kcd    = ws + OFF_KCD;
  float* ai     = ws + OFF_AI;
  float* AT     = ws + OFF_AT;   // aliases mixed (dead after k_conv)
  float* Bm     = ws + OFF_BM;   // aliases hid_bf/qkvw_bf (dead after gemms)
  float* Sall   = ws + OFF_SALL;
  float* core   = ws + OFF_CORE;

  // casts to bf16
  k_cast8<<<(S_LEN*HID/8+255)/256,       256, 0, stream>>>(hid,  hid_bf,  S_LEN*HID/8);
  k_cast8<<<(CONV_DIM*HID/8+255)/256,    256, 0, stream>>>(qkvw, qkvw_bf, CONV_DIM*HID/8);
  k_cast8<<<(VAL_DIM*HID/8+255)/256,     256, 0, stream>>>(zw,   zw_bf,   VAL_DIM*HID/8);
  k_cast8<<<(HID*VAL_DIM/8+255)/256,     256, 0, stream>>>(ow,   ow_bf,   HID*VAL_DIM/8);

  gemm_bf<<<dim3(CONV_DIM/128, S_LEN/128), 256, 0, stream>>>(hid_bf, qkvw_bf, mixed, S_LEN, CONV_DIM, HID);
  gemm_bf<<<dim3(VAL_DIM/128,  S_LEN/128), 256, 0, stream>>>(hid_bf, zw_bf,   zbuf,  S_LEN, VAL_DIM, HID);
  k_ba<<<S_LEN, 128, 0, stream>>>(hid, bw, aw, braw, araw);
  k_beta_g<<<NH*NC, 64, 0, stream>>>(braw, araw, dtb, alog, beta, G);
  k_conv<<<dim3(CONV_DIM/256, S_LEN), 256, 0, stream>>>(mixed, cw, convo);
  k_l2norm<<<dim3(S_LEN, NH/4), 256, 0, stream>>>(convo);
  k_chunk1<<<dim3(NC, NH), 256, 0, stream>>>(convo, G, beta, ai, kcd);
  k_chunk2<<<dim3(NC, NH), 256, 0, stream>>>(convo, kcd, G, AT, Bm);
  k_scan<<<dim3(NH, 8), 256, 0, stream>>>(AT, Bm, Sall);
  k_out<<<dim3(NC, NH), 256, 0, stream>>>(convo, kcd, ai, Sall, G, core);
  k_norm_gate<<<S_LEN*NH/4, 256, 0, stream>>>(core, zbuf, nw, gated_bf);
  gemm_bf<<<dim3(HID/128, S_LEN/128), 256, 0, stream>>>(gated_bf, ow_bf, (float*)d_out, S_LEN, HID, VAL_DIM);
}

// Round 3
// 578.400 us; speedup vs baseline: 3.1043x; 1.4187x over previous
//
#include <hip/hip_runtime.h>
#include <math.h>

#define S_LEN 2048
#define HID 2048
#define NH 16
#define DK 128
#define DV 128
#define CS 64
#define NC 32
#define KEY_DIM 2048
#define VAL_DIM 2048
#define CONV_DIM 6144
#define QSCALE 0.08838834764831845f  /* 1/sqrt(128) */

typedef unsigned short u16;
typedef unsigned int u32;
typedef __bf16 bf16x8 __attribute__((ext_vector_type(8)));
typedef float f32x4 __attribute__((ext_vector_type(4)));

__device__ __forceinline__ float sigmoidf_(float x){ return 1.f/(1.f+expf(-x)); }
__device__ __forceinline__ u16 f2bf(float x){
  u32 u = __float_as_uint(x);
  return (u16)((u + 0x7fffu + ((u>>16)&1u)) >> 16);
}

// ---------------- workspace layout (float units) ----------------
constexpr size_t OFF_HIDBF  = 0;          // bf16 S*HID; dead after gemm z
constexpr size_t OFF_QKVWBF = 2097152;
constexpr size_t OFF_ZWBF   = 8388608;
constexpr size_t OFF_OWBF   = 10485760;
constexpr size_t OFF_GATED  = 12582912;
constexpr size_t OFF_MIXED  = 14680064;   // 12,582,912 fl; ba-partials scratch first, then mixed, then AT
constexpr size_t OFF_CONVO  = 27262976;
constexpr size_t OFF_Z      = 39845888;
constexpr size_t OFF_BRAW   = 44040192;
constexpr size_t OFF_ARAW   = 44072960;
constexpr size_t OFF_BETA   = 44105728;
constexpr size_t OFF_G      = 44138496;
constexpr size_t OFF_KCD    = 44171264;
constexpr size_t OFF_AI     = 48365568;
constexpr size_t OFF_SALL   = 50462720;
constexpr size_t OFF_CORE   = 58851328;   // end: 63,045,632 fl = 252.2 MB
constexpr size_t OFF_AT     = OFF_MIXED;  // alias: written after mixed dead
constexpr size_t OFF_BM     = 0;          // alias: hidbf/qkvwbf dead by then
constexpr size_t OFF_BAPART = OFF_MIXED;  // alias: used before mixed is written

// ---------------- f32 -> bf16 cast (8 elems/thread) ----------------
__global__ __launch_bounds__(256) void k_cast8(const float* __restrict__ in,
                                               u16* __restrict__ out, int n8)
{
  int i = blockIdx.x*256 + threadIdx.x;
  if (i >= n8) return;
  const float4 a = *(const float4*)(in + (size_t)i*8);
  const float4 b = *(const float4*)(in + (size_t)i*8 + 4);
  uint4 o;
  o.x = (u32)f2bf(a.x) | ((u32)f2bf(a.y)<<16);
  o.y = (u32)f2bf(a.z) | ((u32)f2bf(a.w)<<16);
  o.z = (u32)f2bf(b.x) | ((u32)f2bf(b.y)<<16);
  o.w = (u32)f2bf(b.z) | ((u32)f2bf(b.w)<<16);
  *(uint4*)(out + (size_t)i*8) = o;
}

// ---------------- async global->LDS, 16B per lane ----------------
__device__ __forceinline__ void gload16(const u16* g, u16* l){
  __builtin_amdgcn_global_load_lds(
      (__attribute__((address_space(1))) void*)(void*)g,
      (__attribute__((address_space(3))) void*)l, 16, 0, 0);
}

// ---------------- bf16 MFMA GEMM: C[m][n] = sum_k A[m][k]*B[n][k] ----------------
__global__ __launch_bounds__(256) void gemm_bf(const u16* __restrict__ A,
    const u16* __restrict__ B, float* __restrict__ C, int M, int N, int Kd)
{
  __shared__ u16 As[128*32];
  __shared__ u16 Bs[128*32];
  const int tid = threadIdx.x;
  const int w = tid>>6, lane = tid&63;
  const int wr = w>>1, wc = w&1;
  const int row0 = blockIdx.y*128, col0 = blockIdx.x*128;

  f32x4 acc[4][4] = {};

  const int sr = lane>>2;
  const int sk = (lane&3)*8;
  const u16* Ag0 = A + (size_t)(row0 + (2*w  )*16 + sr)*Kd + sk;
  const u16* Ag1 = A + (size_t)(row0 + (2*w+1)*16 + sr)*Kd + sk;
  const u16* Bg0 = B + (size_t)(col0 + (2*w  )*16 + sr)*Kd + sk;
  const u16* Bg1 = B + (size_t)(col0 + (2*w+1)*16 + sr)*Kd + sk;
  u16* Al0 = &As[(2*w  )*16*32];
  u16* Al1 = &As[(2*w+1)*16*32];
  u16* Bl0 = &Bs[(2*w  )*16*32];
  u16* Bl1 = &Bs[(2*w+1)*16*32];

  const int fr = lane&15, fc = (lane>>4)*8;
  const int arow0 = (wr*64 + fr)*32 + fc;
  const int brow0 = (wc*64 + fr)*32 + fc;

  for (int k0=0; k0<Kd; k0+=32){
    __syncthreads();
    gload16(Ag0 + k0, Al0);
    gload16(Ag1 + k0, Al1);
    gload16(Bg0 + k0, Bl0);
    gload16(Bg1 + k0, Bl1);
    __syncthreads();
    bf16x8 af[4], bfr[4];
#pragma unroll
    for (int m=0;m<4;m++) af[m]  = *(const bf16x8*)&As[arow0 + m*16*32];
#pragma unroll
    for (int n=0;n<4;n++) bfr[n] = *(const bf16x8*)&Bs[brow0 + n*16*32];
#pragma unroll
    for (int m=0;m<4;m++)
#pragma unroll
      for (int n=0;n<4;n++)
        acc[m][n] = __builtin_amdgcn_mfma_f32_16x16x32_bf16(af[m], bfr[n], acc[m][n], 0,0,0);
  }

  const int cr = (lane>>4)*4, cc = lane&15;
#pragma unroll
  for (int m=0;m<4;m++)
#pragma unroll
    for (int n=0;n<4;n++){
      float* cp = C + (size_t)(row0 + wr*64 + m*16 + cr)*N + (col0 + wc*64 + n*16 + cc);
#pragma unroll
      for (int j=0;j<4;j++) cp[(size_t)j*N] = acc[m][n][j];
    }
}

// ---------------- b/a projection: split-K tiled GEMM, M=2048 N=32 K=2048 ----------------
#define BA_KS 512
__global__ __launch_bounds__(256) void k_ba_part(const float* __restrict__ hid,
  const float* __restrict__ bw, const float* __restrict__ aw, float* __restrict__ part)
{
  __shared__ float Ash[32][132];
  __shared__ float Wsh[32][132];
  const int t = threadIdx.x;
  const int ty = t>>4, tx = t&15;
  const int s0 = blockIdx.x*32;
  const int k00 = blockIdx.y*BA_KS;
  float acc[2][2] = {{0.f,0.f},{0.f,0.f}};
#pragma unroll 1
  for (int kt=0; kt<BA_KS; kt+=128){
    const int k0 = k00 + kt;
    __syncthreads();
#pragma unroll
    for (int q=0;q<4;q++){
      int idx = t + q*256;
      int r = idx>>5, c4 = (idx&31)*4;
      *(float4*)&Ash[r][c4] = *(const float4*)&hid[(size_t)(s0+r)*HID + k0 + c4];
      const float* wrow = (r<16)? (bw + (size_t)r*HID) : (aw + (size_t)(r-16)*HID);
      *(float4*)&Wsh[r][c4] = *(const float4*)&wrow[k0 + c4];
    }
    __syncthreads();
#pragma unroll
    for (int kq=0;kq<32;kq++){
      float4 a0 = *(const float4*)&Ash[ty*2  ][kq*4];
      float4 a1 = *(const float4*)&Ash[ty*2+1][kq*4];
      float4 w0 = *(const float4*)&Wsh[tx*2  ][kq*4];
      float4 w1 = *(const float4*)&Wsh[tx*2+1][kq*4];
      acc[0][0] += a0.x*w0.x + a0.y*w0.y + a0.z*w0.z + a0.w*w0.w;
      acc[0][1] += a0.x*w1.x + a0.y*w1.y + a0.z*w1.z + a0.w*w1.w;
      acc[1][0] += a1.x*w0.x + a1.y*w0.y + a1.z*w0.z + a1.w*w0.w;
      acc[1][1] += a1.x*w1.x + a1.y*w1.y + a1.z*w1.z + a1.w*w1.w;
    }
  }
  float* pb = part + (size_t)blockIdx.y*S_LEN*32;
#pragma unroll
  for (int i=0;i<2;i++)
#pragma unroll
    for (int j=0;j<2;j++)
      pb[(size_t)(s0+ty*2+i)*32 + tx*2+j] = acc[i][j];
}

__global__ __launch_bounds__(256) void k_ba_red(const float* __restrict__ part,
  float* __restrict__ braw, float* __restrict__ araw)
{
  int idx = blockIdx.x*256 + threadIdx.x;
  if (idx >= S_LEN*32) return;
  float v = part[idx] + part[idx + S_LEN*32] + part[idx + 2*S_LEN*32] + part[idx + 3*S_LEN*32];
  int s = idx>>5, o = idx&31;
  if (o<16) braw[s*NH+o] = v; else araw[s*NH+(o-16)] = v;
}

// ---------------- beta = sigmoid(b); G = within-chunk cumsum of g ----------------
__global__ __launch_bounds__(64) void k_beta_g(const float* __restrict__ braw,
  const float* __restrict__ araw, const float* __restrict__ dtb,
  const float* __restrict__ alog, float* __restrict__ beta, float* __restrict__ G)
{
  const int b = blockIdx.x;
  const int n = b & (NH-1), c = b >> 4;
  const int t = threadIdx.x;
  const int s = c*CS + t;
  float x = araw[s*NH+n] + dtb[n];
  float sp = (x > 20.f) ? x : log1pf(expf(x));
  float g = -expf(alog[n]) * sp;
#pragma unroll
  for (int off=1; off<64; off<<=1){
    float u = __shfl_up(g, off, 64);
    if (t >= off) g += u;
  }
  G[s*NH+n] = g;
  float bb = braw[s*NH+n];
  beta[s*NH+n] = 1.f/(1.f+expf(-bb));
}

// ---------------- depthwise causal conv K=4 + SiLU, 4 s per thread ----------------
__global__ __launch_bounds__(256) void k_conv(const float* __restrict__ mixed,
  const float* __restrict__ cw, float* __restrict__ convo)
{
  const int ch = blockIdx.x*256 + threadIdx.x;
  const int s0 = blockIdx.y*4;
  const float w0=cw[ch*4], w1=cw[ch*4+1], w2=cw[ch*4+2], w3=cw[ch*4+3];
  float m[7];
#pragma unroll
  for (int j=0;j<7;j++){
    int s = s0 + j - 3;
    m[j] = (s>=0) ? mixed[(size_t)s*CONV_DIM+ch] : 0.f;
  }
#pragma unroll
  for (int i=0;i<4;i++){
    float acc = m[i]*w0 + m[i+1]*w1 + m[i+2]*w2 + m[i+3]*w3;
    convo[(size_t)(s0+i)*CONV_DIM+ch] = acc*sigmoidf_(acc);
  }
}

// ---------------- in-place l2norm of q (scaled) and k ----------------
__global__ __launch_bounds__(256) void k_l2norm(float* __restrict__ convo)
{
  const int t = threadIdx.x;
  const int lane = t & 63, w = t >> 6;
  const int s = blockIdx.x;
  const int n = blockIdx.y*4 + w;
  {
    float* q = convo + (size_t)s*CONV_DIM + n*DK;
    float q0 = q[lane], q1 = q[lane+64];
    float ss = q0*q0 + q1*q1;
#pragma unroll
    for (int m=1;m<64;m<<=1) ss += __shfl_xor(ss, m, 64);
    float r = rsqrtf(ss + 1e-6f) * QSCALE;
    q[lane] = q0*r; q[lane+64] = q1*r;
  }
  {
    float* k = convo + (size_t)s*CONV_DIM + KEY_DIM + n*DK;
    float k0 = k[lane], k1 = k[lane+64];
    float ss = k0*k0 + k1*k1;
#pragma unroll
    for (int m=1;m<64;m<<=1) ss += __shfl_xor(ss, m, 64);
    float r = rsqrtf(ss + 1e-6f);
    k[lane] = k0*r; k[lane+64] = k1*r;
  }
}

// ---------------- per (head,chunk): L, attn=(I-L)^-1, ai, value, kcd ----------------
__global__ __launch_bounds__(256) void k_chunk1(float* __restrict__ convo,
  const float* __restrict__ G, const float* __restrict__ beta,
  float* __restrict__ ai_g, float* __restrict__ kcd_g)
{
  __shared__ float KT[128][76];
  __shared__ float LT[64][65];
  __shared__ float reds[4][64];
  __shared__ float Gs[64], bets[64], kes[64];
  const int c = blockIdx.x, n = blockIdx.y;
  const int t = threadIdx.x;
  const int tx = t & 15, ty = t >> 4;
  const int s0 = c*CS;
  if (t < 64){
    float gv = G[(s0+t)*NH+n], bv = beta[(s0+t)*NH+n];
    Gs[t]=gv; bets[t]=bv; kes[t]=bv*expf(gv);
  }
  __syncthreads();
  for (int idx=t; idx<CS*DK; idx+=256){
    int i = idx>>7, d = idx&127;
    KT[d][i] = convo[(size_t)(s0+i)*CONV_DIM + KEY_DIM + n*DK + d];
  }
  __syncthreads();
  {
    const int i0=ty*4, j0=tx*4;
    float l[4][4]={};
    for (int d=0; d<DK; d++){
      float4 ki = *(const float4*)&KT[d][i0];
      float4 kj = *(const float4*)&KT[d][j0];
      float kiv[4]={ki.x,ki.y,ki.z,ki.w};
      float kjv[4]={kj.x,kj.y,kj.z,kj.w};
#pragma unroll
      for (int a=0;a<4;a++)
#pragma unroll
        for (int b=0;b<4;b++) l[a][b] += kiv[a]*kjv[b];
    }
#pragma unroll
    for (int a=0;a<4;a++)
#pragma unroll
      for (int b=0;b<4;b++){
        int i=i0+a, j=j0+b;
        LT[i][j] = (j<i) ? (-bets[i]*l[a][b]*expf(fminf(Gs[i]-Gs[j],10.f))) : 0.f;
      }
  }
  __syncthreads();
  {
    const int i0=ty*4, j0=tx*4;
    float acc[4][4]={};
    for (int d=0; d<DK; d++){
      float4 kj = *(const float4*)&KT[d][j0];
      float kjv[4]={kj.x,kj.y,kj.z,kj.w};
      float qv[4];
#pragma unroll
      for (int a=0;a<4;a++) qv[a] = convo[(size_t)(s0+i0+a)*CONV_DIM + n*DK + d];
#pragma unroll
      for (int a=0;a<4;a++)
#pragma unroll
        for (int b=0;b<4;b++) acc[a][b] += qv[a]*kjv[b];
    }
    size_t ab = ((size_t)(n*NC+c))*CS*CS;
#pragma unroll
    for (int a=0;a<4;a++)
#pragma unroll
      for (int b=0;b<4;b++){
        int i=i0+a, j=j0+b;
        ai_g[ab + i*CS + j] = (j<=i) ? acc[a][b]*expf(fminf(Gs[i]-Gs[j],10.f)) : 0.f;
      }
  }
  __syncthreads();
  if (t==0) LT[0][0]=1.f;
  __syncthreads();
#pragma unroll 1
  for (int i=1;i<64;i++){
    const int j = t&63, pg = t>>6;
    float part=0.f;
    if (j < i){
      for (int p=j+1+pg; p<i; p+=4) part += LT[i][p]*LT[p][j];
    }
    reds[pg][j]=part;
    __syncthreads();
    if (t < 64){
      if (t < i) LT[i][t] += reds[0][t]+reds[1][t]+reds[2][t]+reds[3][t];
      else if (t==i) LT[i][i] = 1.f;
    }
    __syncthreads();
  }
  {
    const int i0=ty*4, d0=tx*8;
    float acc[4][8]={};
    for (int p=0;p<CS;p++){
      float lt[4];
#pragma unroll
      for (int a=0;a<4;a++) lt[a]=LT[i0+a][p];
      const float bp = bets[p];
      const float* vr = convo + (size_t)(s0+p)*CONV_DIM + 2*KEY_DIM + n*DV + d0;
      float4 v0=*(const float4*)vr, v1=*(const float4*)(vr+4);
      float vv[8]={v0.x*bp,v0.y*bp,v0.z*bp,v0.w*bp,v1.x*bp,v1.y*bp,v1.z*bp,v1.w*bp};
#pragma unroll
      for (int a=0;a<4;a++)
#pragma unroll
        for (int b=0;b<8;b++) acc[a][b] += lt[a]*vv[b];
    }
    __syncthreads();
#pragma unroll
    for (int a=0;a<4;a++){
      float* orow = convo + (size_t)(s0+i0+a)*CONV_DIM + 2*KEY_DIM + n*DV + d0;
      *(float4*)orow     = make_float4(acc[a][0],acc[a][1],acc[a][2],acc[a][3]);
      *(float4*)(orow+4) = make_float4(acc[a][4],acc[a][5],acc[a][6],acc[a][7]);
    }
  }
  {
    const int i0=(t&7)*8, d0=(t>>3)*4;
    float acc[8][4]={};
    for (int p=0;p<CS;p++){
      const float ke = kes[p];
      float lt[8];
#pragma unroll
      for (int a=0;a<8;a++) lt[a]=LT[i0+a][p];
      float kv[4];
#pragma unroll
      for (int b=0;b<4;b++) kv[b]=KT[d0+b][p]*ke;
#pragma unroll
      for (int a=0;a<8;a++)
#pragma unroll
        for (int b=0;b<4;b++) acc[a][b]+=lt[a]*kv[b];
    }
    size_t kb = ((size_t)(n*NC+c))*CS*DK;
#pragma unroll
    for (int a=0;a<8;a++)
      *(float4*)&kcd_g[kb + (size_t)(i0+a)*DK + d0] =
          make_float4(acc[a][0],acc[a][1],acc[a][2],acc[a][3]);
  }
}

// ---------------- per (head,chunk): A_c, B_c ----------------
__global__ __launch_bounds__(256) void k_chunk2(const float* __restrict__ convo,
  const float* __restrict__ kcd_g, const float* __restrict__ G,
  float* __restrict__ AT_g, float* __restrict__ B_g)
{
  __shared__ float Ks[32][132], Cs[32][132], Vs[32][132];
  __shared__ float Gsh[64];
  const int c = blockIdx.x, n = blockIdx.y;
  const int t = threadIdx.x;
  const int tx = t&15, ty = t>>4;
  if (t<64) Gsh[t] = G[(c*CS+t)*NH+n];
  __syncthreads();
  const float gl = Gsh[63];
  float accA[8][8]={}, accB[8][8]={};
#pragma unroll 1
  for (int ib=0; ib<2; ib++){
    __syncthreads();
    for (int fi=t; fi<32*32; fi+=256){
      int i = fi>>5, dq=(fi&31)*4;
      int sg = c*CS + ib*32 + i;
      float ef = expf(gl - Gsh[ib*32+i]);
      float4 kv = *(const float4*)&convo[(size_t)sg*CONV_DIM + KEY_DIM + n*DK + dq];
      *(float4*)&Ks[i][dq] = make_float4(kv.x*ef,kv.y*ef,kv.z*ef,kv.w*ef);
      *(float4*)&Cs[i][dq] = *(const float4*)&kcd_g[((size_t)(n*NC+c)*CS + ib*32+i)*DK + dq];
      *(float4*)&Vs[i][dq] = *(const float4*)&convo[(size_t)sg*CONV_DIM + 2*KEY_DIM + n*DV + dq];
    }
    __syncthreads();
    for (int i=0;i<32;i++){
      float krx[8], cpy[8], kry[8], vdx[8];
      float4 u,v;
      u=*(const float4*)&Ks[i][tx*4]; v=*(const float4*)&Ks[i][64+tx*4];
      krx[0]=u.x;krx[1]=u.y;krx[2]=u.z;krx[3]=u.w;krx[4]=v.x;krx[5]=v.y;krx[6]=v.z;krx[7]=v.w;
      u=*(const float4*)&Cs[i][ty*4]; v=*(const float4*)&Cs[i][64+ty*4];
      cpy[0]=u.x;cpy[1]=u.y;cpy[2]=u.z;cpy[3]=u.w;cpy[4]=v.x;cpy[5]=v.y;cpy[6]=v.z;cpy[7]=v.w;
      u=*(const float4*)&Ks[i][ty*4]; v=*(const float4*)&Ks[i][64+ty*4];
      kry[0]=u.x;kry[1]=u.y;kry[2]=u.z;kry[3]=u.w;kry[4]=v.x;kry[5]=v.y;kry[6]=v.z;kry[7]=v.w;
      u=*(const float4*)&Vs[i][tx*4]; v=*(const float4*)&Vs[i][64+tx*4];
      vdx[0]=u.x;vdx[1]=u.y;vdx[2]=u.z;vdx[3]=u.w;vdx[4]=v.x;vdx[5]=v.y;vdx[6]=v.z;vdx[7]=v.w;
#pragma unroll
      for (int a=0;a<8;a++)
#pragma unroll
        for (int b=0;b<8;b++){
          accA[a][b] += cpy[a]*krx[b];
          accB[a][b] += kry[a]*vdx[b];
        }
    }
  }
  const float egl = expf(gl);
  const size_t ab = (size_t)(n*NC+c)*DK*DK;
#pragma unroll
  for (int a=0;a<8;a++){
    int p = (a<4)?(ty*4+a):(64+ty*4+a-4);
#pragma unroll
    for (int bq=0;bq<2;bq++){
      int r0 = (bq==0)?(tx*4):(64+tx*4);
      float o[4];
#pragma unroll
      for (int j=0;j<4;j++){
        int r = r0+j;
        float val = -accA[a][bq*4+j];
        if (p==r) val += egl;
        o[j]=val;
      }
      *(float4*)&AT_g[ab + (size_t)p*DK + r0] = make_float4(o[0],o[1],o[2],o[3]);
    }
  }
  const size_t bb = (size_t)(n*NC+c)*DK*DV;
#pragma unroll
  for (int a=0;a<8;a++){
    int r = (a<4)?(ty*4+a):(64+ty*4+a-4);
#pragma unroll
    for (int bq=0;bq<2;bq++){
      int d0 = (bq==0)?(tx*4):(64+tx*4);
      *(float4*)&B_g[bb + (size_t)r*DV + d0] =
        make_float4(accB[a][bq*4+0],accB[a][bq*4+1],accB[a][bq*4+2],accB[a][bq*4+3]);
    }
  }
}

// ---------------- sequential scan ----------------
__global__ __launch_bounds__(256) void k_scan(const float* __restrict__ AT_g,
  const float* __restrict__ B_g, float* __restrict__ Sall)
{
  __shared__ float Ash[64][132];
  __shared__ float SL[128][20];
  const int n = blockIdx.x, cg = blockIdx.y;
  const int t = threadIdx.x;
  const int r0 = (t&63)*2, d0 = (t>>6)*4;
  for (int idx=t; idx<128*20; idx+=256) (&SL[0][0])[idx]=0.f;
  __syncthreads();
#pragma unroll 1
  for (int c=0;c<NC;c++){
    const size_t mb = (size_t)(n*NC+c)*DK;
#pragma unroll
    for (int rr=0;rr<2;rr++){
      float4 sv = *(float4*)&SL[r0+rr][d0];
      *(float4*)&Sall[(mb + r0+rr)*DV + cg*16 + d0] = sv;
    }
    float acc[2][4]={};
#pragma unroll 1
    for (int pb=0;pb<2;pb++){
      __syncthreads();
      const size_t abase = (mb + pb*64)*DK;
#pragma unroll
      for (int q=0;q<8;q++){
        int fi = t + q*256;
        int p = fi>>5, rq=(fi&31)*4;
        *(float4*)&Ash[p][rq] = *(const float4*)&AT_g[abase + (size_t)p*DK + rq];
      }
      __syncthreads();
      for (int pp=0;pp<64;pp++){
        float a0=Ash[pp][r0], a1=Ash[pp][r0+1];
        float4 sv=*(float4*)&SL[pb*64+pp][d0];
        float s4[4]={sv.x,sv.y,sv.z,sv.w};
#pragma unroll
        for (int dd=0;dd<4;dd++){ acc[0][dd]+=a0*s4[dd]; acc[1][dd]+=a1*s4[dd]; }
      }
    }
    __syncthreads();
    float4 b0=*(const float4*)&B_g[(mb + r0)*DV + cg*16 + d0];
    float4 b1=*(const float4*)&B_g[(mb + r0+1)*DV + cg*16 + d0];
    float4 n0=make_float4(acc[0][0]+b0.x, acc[0][1]+b0.y, acc[0][2]+b0.z, acc[0][3]+b0.w);
    float4 n1=make_float4(acc[1][0]+b1.x, acc[1][1]+b1.y, acc[1][2]+b1.z, acc[1][3]+b1.w);
    *(float4*)&SL[r0][d0]=n0; *(float4*)&SL[r0+1][d0]=n1;
    __syncthreads();
  }
}

// ---------------- outputs ----------------
__global__ __launch_bounds__(256) void k_out(const float* __restrict__ convo,
  const float* __restrict__ kcd_g, const float* __restrict__ ai_g,
  const float* __restrict__ Sall, const float* __restrict__ G,
  float* __restrict__ core)
{
  __shared__ float Ssh[32][132];
  __shared__ float Wsh[64][132];
  __shared__ float egs[64];
  const int c = blockIdx.x, n = blockIdx.y;
  const int t = threadIdx.x;
  const int tx = t&15, ty = t>>4;
  const int i0 = ty*4, d0 = tx*8;
  const int s0 = c*CS;
  if (t<64) egs[t] = expf(G[(s0+t)*NH+n]);
  float wacc[4][8]={}, oacc[4][8]={};
  const size_t mb = (size_t)(n*NC+c)*DK;
  const size_t kb = (size_t)(n*NC+c)*CS*DK;
#pragma unroll 1
  for (int rb=0;rb<4;rb++){
    __syncthreads();
    for (int fi=t; fi<32*32; fi+=256){
      int rr=fi>>5, dq=(fi&31)*4;
      *(float4*)&Ssh[rr][dq] = *(const float4*)&Sall[(mb + rb*32+rr)*DV + dq];
    }
    __syncthreads();
    for (int r2=0;r2<32;r2++){
      int r = rb*32+r2;
      float4 sa=*(const float4*)&Ssh[r2][d0], sb=*(const float4*)&Ssh[r2][d0+4];
      float sv[8]={sa.x,sa.y,sa.z,sa.w,sb.x,sb.y,sb.z,sb.w};
      float qv[4], kv[4];
#pragma unroll
      for (int a=0;a<4;a++){
        qv[a] = convo[(size_t)(s0+i0+a)*CONV_DIM + n*DK + r] * egs[i0+a];
        kv[a] = kcd_g[kb + (size_t)(i0+a)*DK + r];
      }
#pragma unroll
      for (int a=0;a<4;a++)
#pragma unroll
        for (int b=0;b<8;b++){
          oacc[a][b] += qv[a]*sv[b];
          wacc[a][b] += kv[a]*sv[b];
        }
    }
  }
  __syncthreads();
#pragma unroll
  for (int a=0;a<4;a++){
    const float* vr = convo + (size_t)(s0+i0+a)*CONV_DIM + 2*KEY_DIM + n*DV + d0;
    float4 v0=*(const float4*)vr, v1=*(const float4*)(vr+4);
    *(float4*)&Wsh[i0+a][d0]   = make_float4(v0.x-wacc[a][0],v0.y-wacc[a][1],v0.z-wacc[a][2],v0.w-wacc[a][3]);
    *(float4*)&Wsh[i0+a][d0+4] = make_float4(v1.x-wacc[a][4],v1.y-wacc[a][5],v1.z-wacc[a][6],v1.w-wacc[a][7]);
  }
  __syncthreads();
  const size_t aib = (size_t)(n*NC+c)*CS*CS;
  for (int j=0;j<CS;j++){
    float4 w0=*(const float4*)&Wsh[j][d0], w1=*(const float4*)&Wsh[j][d0+4];
    float wv[8]={w0.x,w0.y,w0.z,w0.w,w1.x,w1.y,w1.z,w1.w};
    float av[4];
#pragma unroll
    for (int a=0;a<4;a++) av[a]=ai_g[aib + (size_t)(i0+a)*CS + j];
#pragma unroll
    for (int a=0;a<4;a++)
#pragma unroll
      for (int b=0;b<8;b++) oacc[a][b]+=av[a]*wv[b];
  }
#pragma unroll
  for (int a=0;a<4;a++){
    float* cr = core + (size_t)(s0+i0+a)*VAL_DIM + n*DV + d0;
    *(float4*)cr     = make_float4(oacc[a][0],oacc[a][1],oacc[a][2],oacc[a][3]);
    *(float4*)(cr+4) = make_float4(oacc[a][4],oacc[a][5],oacc[a][6],oacc[a][7]);
  }
}

// ---------------- RMSNorm * norm_w * silu(z) -> bf16 ----------------
__global__ __launch_bounds__(256) void k_norm_gate(const float* __restrict__ core,
  const float* __restrict__ z, const float* __restrict__ nw, u16* __restrict__ gated)
{
  const int t=threadIdx.x, lane=t&63, w=t>>6;
  const int row = blockIdx.x*4 + w;
  const float* cr = core + (size_t)row*DV;
  float c0=cr[lane], c1=cr[lane+64];
  float ss=c0*c0+c1*c1;
#pragma unroll
  for (int m=1;m<64;m<<=1) ss += __shfl_xor(ss,m,64);
  float sc = rsqrtf(ss*(1.f/128.f) + 1e-6f);
  const float* zr = z + (size_t)row*DV;
  float z0=zr[lane], z1=zr[lane+64];
  u16* gr = gated + (size_t)row*DV;
  gr[lane]    = f2bf(c0*sc*nw[lane]    * (z0*sigmoidf_(z0)));
  gr[lane+64] = f2bf(c1*sc*nw[lane+64] * (z1*sigmoidf_(z1)));
}

extern "C" void kernel_launch(void* const* d_in, const int* in_sizes, int n_in,
                              void* d_out, int out_size, void* d_ws, size_t ws_size,
                              hipStream_t stream)
{
  (void)in_sizes; (void)n_in; (void)out_size; (void)ws_size;
  const float* hid  = (const float*)d_in[0];
  const float* qkvw = (const float*)d_in[1];
  const float* zw   = (const float*)d_in[2];
  const float* bw   = (const float*)d_in[3];
  const float* aw   = (const float*)d_in[4];
  const float* ow   = (const float*)d_in[5];
  const float* cw   = (const float*)d_in[6];
  const float* dtb  = (const float*)d_in[7];
  const float* alog = (const float*)d_in[8];
  const float* nw   = (const float*)d_in[9];

  float* ws     = (float*)d_ws;
  u16* hid_bf   = (u16*)(ws + OFF_HIDBF);
  u16* qkvw_bf  = (u16*)(ws + OFF_QKVWBF);
  u16* zw_bf    = (u16*)(ws + OFF_ZWBF);
  u16* ow_bf    = (u16*)(ws + OFF_OWBF);
  u16* gated_bf = (u16*)(ws + OFF_GATED);
  float* mixed  = ws + OFF_MIXED;
  float* convo  = ws + OFF_CONVO;
  float* zbuf   = ws + OFF_Z;
  float* braw   = ws + OFF_BRAW;
  float* araw   = ws + OFF_ARAW;
  float* beta   = ws + OFF_BETA;
  float* G      = ws + OFF_G;
  float* kcd    = ws + OFF_KCD;
  float* ai     = ws + OFF_AI;
  float* AT     = ws + OFF_AT;
  float* Bm     = ws + OFF_BM;
  float* Sall   = ws + OFF_SALL;
  float* core   = ws + OFF_CORE;
  float* bapart = ws + OFF_BAPART;   // scratch in mixed region, consumed before gemm qkv writes it

  // b/a projection first (scratch aliases mixed, which is written later)
  k_ba_part<<<dim3(S_LEN/32, 4), 256, 0, stream>>>(hid, bw, aw, bapart);
  k_ba_red<<<(S_LEN*32+255)/256, 256, 0, stream>>>(bapart, braw, araw);
  k_beta_g<<<NH*NC, 64, 0, stream>>>(braw, araw, dtb, alog, beta, G);

  // casts to bf16
  k_cast8<<<(S_LEN*HID/8+255)/256,    256, 0, stream>>>(hid,  hid_bf,  S_LEN*HID/8);
  k_cast8<<<(CONV_DIM*HID/8+255)/256, 256, 0, stream>>>(qkvw, qkvw_bf, CONV_DIM*HID/8);
  k_cast8<<<(VAL_DIM*HID/8+255)/256,  256, 0, stream>>>(zw,   zw_bf,   VAL_DIM*HID/8);
  k_cast8<<<(HID*VAL_DIM/8+255)/256,  256, 0, stream>>>(ow,   ow_bf,   HID*VAL_DIM/8);

  gemm_bf<<<dim3(CONV_DIM/128, S_LEN/128), 256, 0, stream>>>(hid_bf, qkvw_bf, mixed, S_LEN, CONV_DIM, HID);
  gemm_bf<<<dim3(VAL_DIM/128,  S_LEN/128), 256, 0, stream>>>(hid_bf, zw_bf,   zbuf,  S_LEN, VAL_DIM, HID);
  k_conv<<<dim3(CONV_DIM/256, S_LEN/4), 256, 0, stream>>>(mixed, cw, convo);
  k_l2norm<<<dim3(S_LEN, NH/4), 256, 0, stream>>>(convo);
  k_chunk1<<<dim3(NC, NH), 256, 0, stream>>>(convo, G, beta, ai, kcd);
  k_chunk2<<<dim3(NC, NH), 256, 0, stream>>>(convo, kcd, G, AT, Bm);
  k_scan<<<dim3(NH, 8), 256, 0, stream>>>(AT, Bm, Sall);
  k_out<<<dim3(NC, NH), 256, 0, stream>>>(convo, kcd, ai, Sall, G, core);
  k_norm_gate<<<S_LEN*NH/4, 256, 0, stream>>>(core, zbuf, nw, gated_bf);
  gemm_bf<<<dim3(HID/128, S_LEN/128), 256, 0, stream>>>(gated_bf, ow_bf, (float*)d_out, S_LEN, HID, VAL_DIM);
}

// Round 4
// 497.039 us; speedup vs baseline: 3.6124x; 1.1637x over previous
//
#include <hip/hip_runtime.h>
#include <math.h>

#define S_LEN 2048
#define HID 2048
#define NH 16
#define DK 128
#define DV 128
#define CS 64
#define NC 32
#define KEY_DIM 2048
#define VAL_DIM 2048
#define CONV_DIM 6144
#define QSCALE 0.08838834764831845f  /* 1/sqrt(128) */

typedef unsigned short u16;
typedef unsigned int u32;
typedef __bf16 bf16x8 __attribute__((ext_vector_type(8)));
typedef float f32x4 __attribute__((ext_vector_type(4)));

__device__ __forceinline__ float sigmoidf_(float x){ return 1.f/(1.f+expf(-x)); }
__device__ __forceinline__ u16 f2bf(float x){
  u32 u = __float_as_uint(x);
  return (u16)((u + 0x7fffu + ((u>>16)&1u)) >> 16);
}

// ---------------- workspace layout (float units) ----------------
constexpr size_t OFF_HIDBF  = 0;          // bf16 S*HID; dead after gemm z
constexpr size_t OFF_QKVWBF = 2097152;    // dead after gemm qkv
constexpr size_t OFF_ZWBF   = 8388608;
constexpr size_t OFF_OWBF   = 10485760;
constexpr size_t OFF_GATED  = 12582912;
constexpr size_t OFF_MIXED  = 14680064;   // bapart -> mixed -> ktil
constexpr size_t OFF_CONVO  = 27262976;
constexpr size_t OFF_Z      = 39845888;
constexpr size_t OFF_BRAW   = 44040192;
constexpr size_t OFF_ARAW   = 44072960;
constexpr size_t OFF_BETA   = 44105728;
constexpr size_t OFF_G      = 44138496;
constexpr size_t OFF_KCD    = 44171264;
constexpr size_t OFF_AI     = 48365568;
constexpr size_t OFF_SALL   = 50462720;
constexpr size_t OFF_CORE   = 58851328;   // end: 63,045,632 fl = 252.2 MB
constexpr size_t OFF_BAPART = OFF_MIXED;  // consumed before gemm qkv writes mixed
constexpr size_t OFF_KTIL   = OFF_MIXED;  // written after mixed is dead (post k_conv)
constexpr size_t OFF_VNEW   = 0;          // hid_bf/qkvw_bf region, dead after gemms

// ---------------- f32 -> bf16 cast (8 elems/thread) ----------------
__global__ __launch_bounds__(256) void k_cast8(const float* __restrict__ in,
                                               u16* __restrict__ out, int n8)
{
  int i = blockIdx.x*256 + threadIdx.x;
  if (i >= n8) return;
  const float4 a = *(const float4*)(in + (size_t)i*8);
  const float4 b = *(const float4*)(in + (size_t)i*8 + 4);
  uint4 o;
  o.x = (u32)f2bf(a.x) | ((u32)f2bf(a.y)<<16);
  o.y = (u32)f2bf(a.z) | ((u32)f2bf(a.w)<<16);
  o.z = (u32)f2bf(b.x) | ((u32)f2bf(b.y)<<16);
  o.w = (u32)f2bf(b.z) | ((u32)f2bf(b.w)<<16);
  *(uint4*)(out + (size_t)i*8) = o;
}

// ---------------- async global->LDS, 16B per lane ----------------
__device__ __forceinline__ void gload16(const u16* g, u16* l){
  __builtin_amdgcn_global_load_lds(
      (__attribute__((address_space(1))) void*)(void*)g,
      (__attribute__((address_space(3))) void*)l, 16, 0, 0);
}

// ---------------- bf16 MFMA GEMM: C[m][n] = sum_k A[m][k]*B[n][k] ----------------
__global__ __launch_bounds__(256) void gemm_bf(const u16* __restrict__ A,
    const u16* __restrict__ B, float* __restrict__ C, int M, int N, int Kd)
{
  __shared__ u16 As[128*32];
  __shared__ u16 Bs[128*32];
  const int tid = threadIdx.x;
  const int w = tid>>6, lane = tid&63;
  const int wr = w>>1, wc = w&1;
  const int row0 = blockIdx.y*128, col0 = blockIdx.x*128;

  f32x4 acc[4][4] = {};

  const int sr = lane>>2;
  const int sk = (lane&3)*8;
  const u16* Ag0 = A + (size_t)(row0 + (2*w  )*16 + sr)*Kd + sk;
  const u16* Ag1 = A + (size_t)(row0 + (2*w+1)*16 + sr)*Kd + sk;
  const u16* Bg0 = B + (size_t)(col0 + (2*w  )*16 + sr)*Kd + sk;
  const u16* Bg1 = B + (size_t)(col0 + (2*w+1)*16 + sr)*Kd + sk;
  u16* Al0 = &As[(2*w  )*16*32];
  u16* Al1 = &As[(2*w+1)*16*32];
  u16* Bl0 = &Bs[(2*w  )*16*32];
  u16* Bl1 = &Bs[(2*w+1)*16*32];

  const int fr = lane&15, fc = (lane>>4)*8;
  const int arow0 = (wr*64 + fr)*32 + fc;
  const int brow0 = (wc*64 + fr)*32 + fc;

  for (int k0=0; k0<Kd; k0+=32){
    __syncthreads();
    gload16(Ag0 + k0, Al0);
    gload16(Ag1 + k0, Al1);
    gload16(Bg0 + k0, Bl0);
    gload16(Bg1 + k0, Bl1);
    __syncthreads();
    bf16x8 af[4], bfr[4];
#pragma unroll
    for (int m=0;m<4;m++) af[m]  = *(const bf16x8*)&As[arow0 + m*16*32];
#pragma unroll
    for (int n=0;n<4;n++) bfr[n] = *(const bf16x8*)&Bs[brow0 + n*16*32];
#pragma unroll
    for (int m=0;m<4;m++)
#pragma unroll
      for (int n=0;n<4;n++)
        acc[m][n] = __builtin_amdgcn_mfma_f32_16x16x32_bf16(af[m], bfr[n], acc[m][n], 0,0,0);
  }

  const int cr = (lane>>4)*4, cc = lane&15;
#pragma unroll
  for (int m=0;m<4;m++)
#pragma unroll
    for (int n=0;n<4;n++){
      float* cp = C + (size_t)(row0 + wr*64 + m*16 + cr)*N + (col0 + wc*64 + n*16 + cc);
#pragma unroll
      for (int j=0;j<4;j++) cp[(size_t)j*N] = acc[m][n][j];
    }
}

// ---------------- b/a projection: split-K tiled GEMM, M=2048 N=32 K=2048 ----------------
#define BA_KS 512
__global__ __launch_bounds__(256) void k_ba_part(const float* __restrict__ hid,
  const float* __restrict__ bw, const float* __restrict__ aw, float* __restrict__ part)
{
  __shared__ float Ash[32][132];
  __shared__ float Wsh[32][132];
  const int t = threadIdx.x;
  const int ty = t>>4, tx = t&15;
  const int s0 = blockIdx.x*32;
  const int k00 = blockIdx.y*BA_KS;
  float acc[2][2] = {{0.f,0.f},{0.f,0.f}};
#pragma unroll 1
  for (int kt=0; kt<BA_KS; kt+=128){
    const int k0 = k00 + kt;
    __syncthreads();
#pragma unroll
    for (int q=0;q<4;q++){
      int idx = t + q*256;
      int r = idx>>5, c4 = (idx&31)*4;
      *(float4*)&Ash[r][c4] = *(const float4*)&hid[(size_t)(s0+r)*HID + k0 + c4];
      const float* wrow = (r<16)? (bw + (size_t)r*HID) : (aw + (size_t)(r-16)*HID);
      *(float4*)&Wsh[r][c4] = *(const float4*)&wrow[k0 + c4];
    }
    __syncthreads();
#pragma unroll
    for (int kq=0;kq<32;kq++){
      float4 a0 = *(const float4*)&Ash[ty*2  ][kq*4];
      float4 a1 = *(const float4*)&Ash[ty*2+1][kq*4];
      float4 w0 = *(const float4*)&Wsh[tx*2  ][kq*4];
      float4 w1 = *(const float4*)&Wsh[tx*2+1][kq*4];
      acc[0][0] += a0.x*w0.x + a0.y*w0.y + a0.z*w0.z + a0.w*w0.w;
      acc[0][1] += a0.x*w1.x + a0.y*w1.y + a0.z*w1.z + a0.w*w1.w;
      acc[1][0] += a1.x*w0.x + a1.y*w0.y + a1.z*w0.z + a1.w*w0.w;
      acc[1][1] += a1.x*w1.x + a1.y*w1.y + a1.z*w1.z + a1.w*w1.w;
    }
  }
  float* pb = part + (size_t)blockIdx.y*S_LEN*32;
#pragma unroll
  for (int i=0;i<2;i++)
#pragma unroll
    for (int j=0;j<2;j++)
      pb[(size_t)(s0+ty*2+i)*32 + tx*2+j] = acc[i][j];
}

__global__ __launch_bounds__(256) void k_ba_red(const float* __restrict__ part,
  float* __restrict__ braw, float* __restrict__ araw)
{
  int idx = blockIdx.x*256 + threadIdx.x;
  if (idx >= S_LEN*32) return;
  float v = part[idx] + part[idx + S_LEN*32] + part[idx + 2*S_LEN*32] + part[idx + 3*S_LEN*32];
  int s = idx>>5, o = idx&31;
  if (o<16) braw[s*NH+o] = v; else araw[s*NH+(o-16)] = v;
}

// ---------------- beta = sigmoid(b); G = within-chunk cumsum of g ----------------
__global__ __launch_bounds__(64) void k_beta_g(const float* __restrict__ braw,
  const float* __restrict__ araw, const float* __restrict__ dtb,
  const float* __restrict__ alog, float* __restrict__ beta, float* __restrict__ G)
{
  const int b = blockIdx.x;
  const int n = b & (NH-1), c = b >> 4;
  const int t = threadIdx.x;
  const int s = c*CS + t;
  float x = araw[s*NH+n] + dtb[n];
  float sp = (x > 20.f) ? x : log1pf(expf(x));
  float g = -expf(alog[n]) * sp;
#pragma unroll
  for (int off=1; off<64; off<<=1){
    float u = __shfl_up(g, off, 64);
    if (t >= off) g += u;
  }
  G[s*NH+n] = g;
  float bb = braw[s*NH+n];
  beta[s*NH+n] = 1.f/(1.f+expf(-bb));
}

// ---------------- depthwise causal conv K=4 + SiLU, 4 s per thread ----------------
__global__ __launch_bounds__(256) void k_conv(const float* __restrict__ mixed,
  const float* __restrict__ cw, float* __restrict__ convo)
{
  const int ch = blockIdx.x*256 + threadIdx.x;
  const int s0 = blockIdx.y*4;
  const float w0=cw[ch*4], w1=cw[ch*4+1], w2=cw[ch*4+2], w3=cw[ch*4+3];
  float m[7];
#pragma unroll
  for (int j=0;j<7;j++){
    int s = s0 + j - 3;
    m[j] = (s>=0) ? mixed[(size_t)s*CONV_DIM+ch] : 0.f;
  }
#pragma unroll
  for (int i=0;i<4;i++){
    float acc = m[i]*w0 + m[i+1]*w1 + m[i+2]*w2 + m[i+3]*w3;
    convo[(size_t)(s0+i)*CONV_DIM+ch] = acc*sigmoidf_(acc);
  }
}

// ---------------- in-place l2norm of q (scaled) and k ----------------
__global__ __launch_bounds__(256) void k_l2norm(float* __restrict__ convo)
{
  const int t = threadIdx.x;
  const int lane = t & 63, w = t >> 6;
  const int s = blockIdx.x;
  const int n = blockIdx.y*4 + w;
  {
    float* q = convo + (size_t)s*CONV_DIM + n*DK;
    float q0 = q[lane], q1 = q[lane+64];
    float ss = q0*q0 + q1*q1;
#pragma unroll
    for (int m=1;m<64;m<<=1) ss += __shfl_xor(ss, m, 64);
    float r = rsqrtf(ss + 1e-6f) * QSCALE;
    q[lane] = q0*r; q[lane+64] = q1*r;
  }
  {
    float* k = convo + (size_t)s*CONV_DIM + KEY_DIM + n*DK;
    float k0 = k[lane], k1 = k[lane+64];
    float ss = k0*k0 + k1*k1;
#pragma unroll
    for (int m=1;m<64;m<<=1) ss += __shfl_xor(ss, m, 64);
    float r = rsqrtf(ss + 1e-6f);
    k[lane] = k0*r; k[lane+64] = k1*r;
  }
}

// ---------------- per (head,chunk): L, attn=(I-L)^-1, ai, value, kcd, ktil ----------------
__global__ __launch_bounds__(256) void k_chunk1(float* __restrict__ convo,
  const float* __restrict__ G, const float* __restrict__ beta,
  float* __restrict__ ai_g, float* __restrict__ kcd_g, float* __restrict__ ktil_g)
{
  __shared__ float KT[128][76];
  __shared__ float LT[64][65];
  __shared__ float reds[4][64];
  __shared__ float Gs[64], bets[64], kes[64], eds_s[64];
  const int c = blockIdx.x, n = blockIdx.y;
  const int t = threadIdx.x;
  const int tx = t & 15, ty = t >> 4;
  const int s0 = c*CS;
  if (t < 64){
    float gv = G[(s0+t)*NH+n], bv = beta[(s0+t)*NH+n];
    Gs[t]=gv; bets[t]=bv; kes[t]=bv*expf(gv);
  }
  __syncthreads();
  if (t < 64) eds_s[t] = expf(Gs[63]-Gs[t]);
  for (int idx=t; idx<CS*DK; idx+=256){
    int i = idx>>7, d = idx&127;
    KT[d][i] = convo[(size_t)(s0+i)*CONV_DIM + KEY_DIM + n*DK + d];
  }
  __syncthreads();
  {
    const int i0=ty*4, j0=tx*4;
    float l[4][4]={};
    for (int d=0; d<DK; d++){
      float4 ki = *(const float4*)&KT[d][i0];
      float4 kj = *(const float4*)&KT[d][j0];
      float kiv[4]={ki.x,ki.y,ki.z,ki.w};
      float kjv[4]={kj.x,kj.y,kj.z,kj.w};
#pragma unroll
      for (int a=0;a<4;a++)
#pragma unroll
        for (int b=0;b<4;b++) l[a][b] += kiv[a]*kjv[b];
    }
#pragma unroll
    for (int a=0;a<4;a++)
#pragma unroll
      for (int b=0;b<4;b++){
        int i=i0+a, j=j0+b;
        LT[i][j] = (j<i) ? (-bets[i]*l[a][b]*expf(fminf(Gs[i]-Gs[j],10.f))) : 0.f;
      }
  }
  __syncthreads();
  {
    const int i0=ty*4, j0=tx*4;
    float acc[4][4]={};
    for (int d=0; d<DK; d++){
      float4 kj = *(const float4*)&KT[d][j0];
      float kjv[4]={kj.x,kj.y,kj.z,kj.w};
      float qv[4];
#pragma unroll
      for (int a=0;a<4;a++) qv[a] = convo[(size_t)(s0+i0+a)*CONV_DIM + n*DK + d];
#pragma unroll
      for (int a=0;a<4;a++)
#pragma unroll
        for (int b=0;b<4;b++) acc[a][b] += qv[a]*kjv[b];
    }
    size_t ab = ((size_t)(n*NC+c))*CS*CS;
#pragma unroll
    for (int a=0;a<4;a++)
#pragma unroll
      for (int b=0;b<4;b++){
        int i=i0+a, j=j0+b;
        ai_g[ab + i*CS + j] = (j<=i) ? acc[a][b]*expf(fminf(Gs[i]-Gs[j],10.f)) : 0.f;
      }
  }
  __syncthreads();
  if (t==0) LT[0][0]=1.f;
  __syncthreads();
#pragma unroll 1
  for (int i=1;i<64;i++){
    const int j = t&63, pg = t>>6;
    float part=0.f;
    if (j < i){
      for (int p=j+1+pg; p<i; p+=4) part += LT[i][p]*LT[p][j];
    }
    reds[pg][j]=part;
    __syncthreads();
    if (t < 64){
      if (t < i) LT[i][t] += reds[0][t]+reds[1][t]+reds[2][t]+reds[3][t];
      else if (t==i) LT[i][i] = 1.f;
    }
    __syncthreads();
  }
  {
    const int i0=ty*4, d0=tx*8;
    float acc[4][8]={};
    for (int p=0;p<CS;p++){
      float lt[4];
#pragma unroll
      for (int a=0;a<4;a++) lt[a]=LT[i0+a][p];
      const float bp = bets[p];
      const float* vr = convo + (size_t)(s0+p)*CONV_DIM + 2*KEY_DIM + n*DV + d0;
      float4 v0=*(const float4*)vr, v1=*(const float4*)(vr+4);
      float vv[8]={v0.x*bp,v0.y*bp,v0.z*bp,v0.w*bp,v1.x*bp,v1.y*bp,v1.z*bp,v1.w*bp};
#pragma unroll
      for (int a=0;a<4;a++)
#pragma unroll
        for (int b=0;b<8;b++) acc[a][b] += lt[a]*vv[b];
    }
    __syncthreads();
#pragma unroll
    for (int a=0;a<4;a++){
      float* orow = convo + (size_t)(s0+i0+a)*CONV_DIM + 2*KEY_DIM + n*DV + d0;
      *(float4*)orow     = make_float4(acc[a][0],acc[a][1],acc[a][2],acc[a][3]);
      *(float4*)(orow+4) = make_float4(acc[a][4],acc[a][5],acc[a][6],acc[a][7]);
    }
  }
  {
    const int i0=(t&7)*8, d0=(t>>3)*4;
    float acc[8][4]={};
    for (int p=0;p<CS;p++){
      const float ke = kes[p];
      float lt[8];
#pragma unroll
      for (int a=0;a<8;a++) lt[a]=LT[i0+a][p];
      float kv[4];
#pragma unroll
      for (int b=0;b<4;b++) kv[b]=KT[d0+b][p]*ke;
#pragma unroll
      for (int a=0;a<8;a++)
#pragma unroll
        for (int b=0;b<4;b++) acc[a][b]+=lt[a]*kv[b];
    }
    size_t kb = ((size_t)(n*NC+c))*CS*DK;
#pragma unroll
    for (int a=0;a<8;a++)
      *(float4*)&kcd_g[kb + (size_t)(i0+a)*DK + d0] =
          make_float4(acc[a][0],acc[a][1],acc[a][2],acc[a][3]);
    // ktil = k * exp(gl - g_i), packed [n][c][i][d]
#pragma unroll
    for (int a=0;a<8;a++){
      float ed = eds_s[i0+a];
      *(float4*)&ktil_g[kb + (size_t)(i0+a)*DK + d0] = make_float4(
        KT[d0][i0+a]*ed, KT[d0+1][i0+a]*ed, KT[d0+2][i0+a]*ed, KT[d0+3][i0+a]*ed);
    }
  }
}

// ---------------- factored sequential scan ----------------
// per (head n, col-group cg of 8 V-cols):
//   S_pre -> Sall; W = KCD*S; V_new = value - W -> vnew; S = e^gl*S + Ktil^T*V_new
#define CG 16
__global__ __launch_bounds__(256,1) void k_scan2(
  const float* __restrict__ convo, const float* __restrict__ kcd_g,
  const float* __restrict__ ktil_g, const float* __restrict__ G,
  float* __restrict__ Sall, float* __restrict__ vnew)
{
  __shared__ float S[128][12];
  __shared__ float Kt[2][64][130];
  __shared__ float Vs[64][12];
  __shared__ float Wp[4][64][12];
  const int n = blockIdx.x, cg = blockIdx.y;
  const int t = threadIdx.x;
  const int li = t & 63, pg = t >> 6;   // W-phase: W-row li, r-range pg*32
  const int ur = t & 127, uh = t >> 7;  // update: S-row ur, col-half uh
  const int d0 = cg*8;
  const int ki = t>>2, kr = (t&3)*32;   // Ktil staging map

  for (int idx=t; idx<128*12; idx+=256) (&S[0][0])[idx]=0.f;

  float4 ktn[8], kcn[8];
  float2 valn;
  {
    const size_t kb = ((size_t)(n*NC))*CS*DK;
#pragma unroll
    for (int j=0;j<8;j++) ktn[j] = *(const float4*)&ktil_g[kb + (size_t)ki*DK + kr + j*4];
#pragma unroll
    for (int j=0;j<8;j++) kcn[j] = *(const float4*)&kcd_g[kb + (size_t)li*DK + pg*32 + j*4];
    valn = *(const float2*)&convo[(size_t)li*CONV_DIM + 2*KEY_DIM + n*DV + d0 + pg*2];
  }
  __syncthreads();

#pragma unroll 1
  for (int c=0;c<NC;c++){
    const int s0 = c*CS;
    const int buf = c&1;
    // 1. stage Ktil(c) into LDS (stride 130 -> conflict-free column reads)
#pragma unroll
    for (int j=0;j<8;j++){
      *(float2*)&Kt[buf][ki][kr + j*4]     = make_float2(ktn[j].x, ktn[j].y);
      *(float2*)&Kt[buf][ki][kr + j*4 + 2] = make_float2(ktn[j].z, ktn[j].w);
    }
    // 2. S_pre -> Sall
    const size_t mb = (size_t)(n*NC+c)*DK;
    {
      float4 sv = *(float4*)&S[ur][uh*4];
      *(float4*)&Sall[(mb + ur)*DV + d0 + uh*4] = sv;
    }
    // 3. W partials: W[li][0..7] over r in [pg*32, pg*32+32)
    float w0=0,w1=0,w2=0,w3=0,w4=0,w5=0,w6=0,w7=0;
#pragma unroll
    for (int q=0;q<8;q++){
      float kq[4] = {kcn[q].x,kcn[q].y,kcn[q].z,kcn[q].w};
#pragma unroll
      for (int e=0;e<4;e++){
        int r = pg*32 + q*4 + e;
        float4 sa = *(float4*)&S[r][0];
        float4 sb = *(float4*)&S[r][4];
        w0 += kq[e]*sa.x; w1 += kq[e]*sa.y; w2 += kq[e]*sa.z; w3 += kq[e]*sa.w;
        w4 += kq[e]*sb.x; w5 += kq[e]*sb.y; w6 += kq[e]*sb.z; w7 += kq[e]*sb.w;
      }
    }
    *(float4*)&Wp[pg][li][0] = make_float4(w0,w1,w2,w3);
    *(float4*)&Wp[pg][li][4] = make_float4(w4,w5,w6,w7);
    // 4. issue next-chunk Ktil/KCD loads
    const int cn = (c+1<NC)?(c+1):c;
    const size_t kbn = ((size_t)(n*NC+cn))*CS*DK;
#pragma unroll
    for (int j=0;j<8;j++) ktn[j] = *(const float4*)&ktil_g[kbn + (size_t)ki*DK + kr + j*4];
#pragma unroll
    for (int j=0;j<8;j++) kcn[j] = *(const float4*)&kcd_g[kbn + (size_t)li*DK + pg*32 + j*4];
    __syncthreads();   // B1
    // 5. V_new for cols pg*2, pg*2+1
    float vn0 = valn.x - (Wp[0][li][pg*2  ]+Wp[1][li][pg*2  ]+Wp[2][li][pg*2  ]+Wp[3][li][pg*2  ]);
    float vn1 = valn.y - (Wp[0][li][pg*2+1]+Wp[1][li][pg*2+1]+Wp[2][li][pg*2+1]+Wp[3][li][pg*2+1]);
    *(float2*)&Vs[li][pg*2] = make_float2(vn0,vn1);
    *(float2*)&vnew[((size_t)(n*NC+c)*CS + li)*DV + d0 + pg*2] = make_float2(vn0,vn1);
    // 6. issue next-chunk value load
    valn = *(const float2*)&convo[(size_t)(cn*CS+li)*CONV_DIM + 2*KEY_DIM + n*DV + d0 + pg*2];
    const float egl = expf(G[(s0+CS-1)*NH + n]);
    __syncthreads();   // B2
    // 7. S = egl*S + Ktil^T * V_new
    {
      float4 sv = *(float4*)&S[ur][uh*4];
      float a0=sv.x*egl, a1=sv.y*egl, a2=sv.z*egl, a3=sv.w*egl;
#pragma unroll
      for (int i=0;i<64;i++){
        float kt = Kt[buf][i][ur];
        float4 vb = *(float4*)&Vs[i][uh*4];
        a0 += kt*vb.x; a1 += kt*vb.y; a2 += kt*vb.z; a3 += kt*vb.w;
      }
      *(float4*)&S[ur][uh*4] = make_float4(a0,a1,a2,a3);
    }
    __syncthreads();   // B3
  }
}

// ---------------- outputs: out = (q*e^g) @ S_pre + ai @ V_new ----------------
__global__ __launch_bounds__(256) void k_out(const float* __restrict__ convo,
  const float* __restrict__ vnew, const float* __restrict__ ai_g,
  const float* __restrict__ Sall, const float* __restrict__ G,
  float* __restrict__ core)
{
  __shared__ float Ssh[32][132];
  __shared__ float Wsh[64][132];   // q~ first, then V_new
  __shared__ float egs[64];
  const int c = blockIdx.x, n = blockIdx.y;
  const int t = threadIdx.x;
  const int tx = t&15, ty = t>>4;
  const int i0 = ty*4, d0 = tx*8;
  const int s0 = c*CS;
  if (t<64) egs[t] = expf(G[(s0+t)*NH+n]);
  __syncthreads();
  // stage q~ = q * e^g into Wsh
  for (int fi=t; fi<64*32; fi+=256){
    int i=fi>>5, rq=(fi&31)*4;
    float4 qv = *(const float4*)&convo[(size_t)(s0+i)*CONV_DIM + n*DK + rq];
    float e = egs[i];
    *(float4*)&Wsh[i][rq] = make_float4(qv.x*e,qv.y*e,qv.z*e,qv.w*e);
  }
  float oacc[4][8]={};
  const size_t mb = (size_t)(n*NC+c)*DK;
#pragma unroll 1
  for (int rb=0;rb<4;rb++){
    __syncthreads();
    for (int fi=t; fi<32*32; fi+=256){
      int rr=fi>>5, dq=(fi&31)*4;
      *(float4*)&Ssh[rr][dq] = *(const float4*)&Sall[(mb + rb*32+rr)*DV + dq];
    }
    __syncthreads();
    for (int r2=0;r2<32;r2++){
      int r = rb*32+r2;
      float4 sa=*(const float4*)&Ssh[r2][d0], sb=*(const float4*)&Ssh[r2][d0+4];
      float sv[8]={sa.x,sa.y,sa.z,sa.w,sb.x,sb.y,sb.z,sb.w};
      float qv[4];
#pragma unroll
      for (int a=0;a<4;a++) qv[a] = Wsh[i0+a][r];
#pragma unroll
      for (int a=0;a<4;a++)
#pragma unroll
        for (int b=0;b<8;b++) oacc[a][b] += qv[a]*sv[b];
    }
  }
  __syncthreads();
  // overwrite Wsh with V_new (packed, coalesced)
  for (int fi=t; fi<64*32; fi+=256){
    int i=fi>>5, dq=(fi&31)*4;
    *(float4*)&Wsh[i][dq] = *(const float4*)&vnew[((size_t)(n*NC+c)*CS + i)*DV + dq];
  }
  __syncthreads();
  const size_t aib = (size_t)(n*NC+c)*CS*CS;
  for (int j=0;j<CS;j++){
    float4 w0=*(const float4*)&Wsh[j][d0], w1=*(const float4*)&Wsh[j][d0+4];
    float wv[8]={w0.x,w0.y,w0.z,w0.w,w1.x,w1.y,w1.z,w1.w};
    float av[4];
#pragma unroll
    for (int a=0;a<4;a++) av[a]=ai_g[aib + (size_t)(i0+a)*CS + j];
#pragma unroll
    for (int a=0;a<4;a++)
#pragma unroll
      for (int b=0;b<8;b++) oacc[a][b]+=av[a]*wv[b];
  }
#pragma unroll
  for (int a=0;a<4;a++){
    float* cr = core + (size_t)(s0+i0+a)*VAL_DIM + n*DV + d0;
    *(float4*)cr     = make_float4(oacc[a][0],oacc[a][1],oacc[a][2],oacc[a][3]);
    *(float4*)(cr+4) = make_float4(oacc[a][4],oacc[a][5],oacc[a][6],oacc[a][7]);
  }
}

// ---------------- RMSNorm * norm_w * silu(z) -> bf16 ----------------
__global__ __launch_bounds__(256) void k_norm_gate(const float* __restrict__ core,
  const float* __restrict__ z, const float* __restrict__ nw, u16* __restrict__ gated)
{
  const int t=threadIdx.x, lane=t&63, w=t>>6;
  const int row = blockIdx.x*4 + w;
  const float* cr = core + (size_t)row*DV;
  float c0=cr[lane], c1=cr[lane+64];
  float ss=c0*c0+c1*c1;
#pragma unroll
  for (int m=1;m<64;m<<=1) ss += __shfl_xor(ss,m,64);
  float sc = rsqrtf(ss*(1.f/128.f) + 1e-6f);
  const float* zr = z + (size_t)row*DV;
  float z0=zr[lane], z1=zr[lane+64];
  u16* gr = gated + (size_t)row*DV;
  gr[lane]    = f2bf(c0*sc*nw[lane]    * (z0*sigmoidf_(z0)));
  gr[lane+64] = f2bf(c1*sc*nw[lane+64] * (z1*sigmoidf_(z1)));
}

extern "C" void kernel_launch(void* const* d_in, const int* in_sizes, int n_in,
                              void* d_out, int out_size, void* d_ws, size_t ws_size,
                              hipStream_t stream)
{
  (void)in_sizes; (void)n_in; (void)out_size; (void)ws_size;
  const float* hid  = (const float*)d_in[0];
  const float* qkvw = (const float*)d_in[1];
  const float* zw   = (const float*)d_in[2];
  const float* bw   = (const float*)d_in[3];
  const float* aw   = (const float*)d_in[4];
  const float* ow   = (const float*)d_in[5];
  const float* cw   = (const float*)d_in[6];
  const float* dtb  = (const float*)d_in[7];
  const float* alog = (const float*)d_in[8];
  const float* nw   = (const float*)d_in[9];

  float* ws     = (float*)d_ws;
  u16* hid_bf   = (u16*)(ws + OFF_HIDBF);
  u16* qkvw_bf  = (u16*)(ws + OFF_QKVWBF);
  u16* zw_bf    = (u16*)(ws + OFF_ZWBF);
  u16* ow_bf    = (u16*)(ws + OFF_OWBF);
  u16* gated_bf = (u16*)(ws + OFF_GATED);
  float* mixed  = ws + OFF_MIXED;
  float* convo  = ws + OFF_CONVO;
  float* zbuf   = ws + OFF_Z;
  float* braw   = ws + OFF_BRAW;
  float* araw   = ws + OFF_ARAW;
  float* beta   = ws + OFF_BETA;
  float* G      = ws + OFF_G;
  float* kcd    = ws + OFF_KCD;
  float* ai     = ws + OFF_AI;
  float* Sall   = ws + OFF_SALL;
  float* core   = ws + OFF_CORE;
  float* bapart = ws + OFF_BAPART;
  float* ktil   = ws + OFF_KTIL;
  float* vnew   = ws + OFF_VNEW;

  // b/a projection first (scratch aliases mixed, consumed before gemm qkv)
  k_ba_part<<<dim3(S_LEN/32, 4), 256, 0, stream>>>(hid, bw, aw, bapart);
  k_ba_red<<<(S_LEN*32+255)/256, 256, 0, stream>>>(bapart, braw, araw);
  k_beta_g<<<NH*NC, 64, 0, stream>>>(braw, araw, dtb, alog, beta, G);

  // casts to bf16
  k_cast8<<<(S_LEN*HID/8+255)/256,    256, 0, stream>>>(hid,  hid_bf,  S_LEN*HID/8);
  k_cast8<<<(CONV_DIM*HID/8+255)/256, 256, 0, stream>>>(qkvw, qkvw_bf, CONV_DIM*HID/8);
  k_cast8<<<(VAL_DIM*HID/8+255)/256,  256, 0, stream>>>(zw,   zw_bf,   VAL_DIM*HID/8);
  k_cast8<<<(HID*VAL_DIM/8+255)/256,  256, 0, stream>>>(ow,   ow_bf,   HID*VAL_DIM/8);

  gemm_bf<<<dim3(CONV_DIM/128, S_LEN/128), 256, 0, stream>>>(hid_bf, qkvw_bf, mixed, S_LEN, CONV_DIM, HID);
  gemm_bf<<<dim3(VAL_DIM/128,  S_LEN/128), 256, 0, stream>>>(hid_bf, zw_bf,   zbuf,  S_LEN, VAL_DIM, HID);
  k_conv<<<dim3(CONV_DIM/256, S_LEN/4), 256, 0, stream>>>(mixed, cw, convo);
  k_l2norm<<<dim3(S_LEN, NH/4), 256, 0, stream>>>(convo);
  k_chunk1<<<dim3(NC, NH), 256, 0, stream>>>(convo, G, beta, ai, kcd, ktil);
  k_scan2<<<dim3(NH, CG), 256, 0, stream>>>(convo, kcd, ktil, G, Sall, vnew);
  k_out<<<dim3(NC, NH), 256, 0, stream>>>(convo, vnew, ai, Sall, G, core);
  k_norm_gate<<<S_LEN*NH/4, 256, 0, stream>>>(core, zbuf, nw, gated_bf);
  gemm_bf<<<dim3(HID/128, S_LEN/128), 256, 0, stream>>>(gated_bf, ow_bf, (float*)d_out, S_LEN, HID, VAL_DIM);
}